// Round 1
// baseline (771.156 us; speedup 1.0000x reference)
//
#include <hip/hip_runtime.h>
#include <math.h>

#define NN 16384      // B*S nodes
#define DD 256        // model dim
#define HH 8          // heads
#define HDIM 32       // head dim
#define EE 262144     // edges
#define D3 768        // 3*D
#define QSCALE 0.17677669529663687f   // 1/sqrt(32)
#define EXPN1 0.36787944117144233f    // exp(-1)
#define LN_EPS 1e-12f

// ---------------- node mask ----------------
__global__ void node_mask_kernel(const float* __restrict__ am, float* __restrict__ nmask) {
    int i = blockIdx.x * 256 + threadIdx.x;
    nmask[i] = (am[i] >= 0.0f) ? 1.0f : 0.0f;
}

// ---------------- tiled fp32 GEMM: C = A[M,K] @ B[K,Nc] + bias (+resid), q-scale on first scale_cols ----
__global__ __launch_bounds__(256) void gemm_kernel(
        const float* __restrict__ A, const float* __restrict__ B,
        const float* __restrict__ bias, const float* __restrict__ resid,
        float* __restrict__ C, int M, int Nc, int K,
        int scale_cols, float scale) {
    __shared__ float As[16][68];
    __shared__ float Bs[16][68];
    const int tid = threadIdx.x;
    const int tx = tid & 15, ty = tid >> 4;
    const int row0 = blockIdx.y * 64;
    const int col0 = blockIdx.x * 64;
    float acc[4][4] = {};
    for (int k0 = 0; k0 < K; k0 += 16) {
        {
            int r = tid >> 2;
            int kk = (tid & 3) * 4;
            float4 av = *(const float4*)(A + (size_t)(row0 + r) * K + k0 + kk);
            As[kk + 0][r] = av.x; As[kk + 1][r] = av.y;
            As[kk + 2][r] = av.z; As[kk + 3][r] = av.w;
        }
        {
            int kk = tid >> 4;
            int c = (tid & 15) * 4;
            float4 bv = *(const float4*)(B + (size_t)(k0 + kk) * Nc + col0 + c);
            *(float4*)&Bs[kk][c] = bv;
        }
        __syncthreads();
        #pragma unroll
        for (int k = 0; k < 16; ++k) {
            float4 a4 = *(const float4*)&As[k][ty * 4];
            float4 b4 = *(const float4*)&Bs[k][tx * 4];
            float av[4] = {a4.x, a4.y, a4.z, a4.w};
            float bv[4] = {b4.x, b4.y, b4.z, b4.w};
            #pragma unroll
            for (int i = 0; i < 4; ++i)
                #pragma unroll
                for (int j = 0; j < 4; ++j)
                    acc[i][j] += av[i] * bv[j];
        }
        __syncthreads();
    }
    #pragma unroll
    for (int i = 0; i < 4; ++i) {
        int r = row0 + ty * 4 + i;
        #pragma unroll
        for (int j = 0; j < 4; ++j) {
            int c = col0 + tx * 4 + j;
            float v = acc[i][j] + bias[c];
            if (c < scale_cols) v *= scale;
            if (resid) v += resid[(size_t)r * Nc + c];
            C[(size_t)r * Nc + c] = v;
        }
    }
}

// ---------------- per-(edge,head) scores: dot(k[src], q[dst]) ----------------
__global__ void edge_score_kernel(const float* __restrict__ qkv,
                                  const int* __restrict__ src, const int* __restrict__ dst,
                                  const float* __restrict__ nmask, float* __restrict__ scores) {
    int idx = blockIdx.x * 256 + threadIdx.x;   // e*8 + h
    int e = idx >> 3, h = idx & 7;
    int s = src[e], d = dst[e];
    const float4* kp = (const float4*)(qkv + (size_t)s * D3 + DD + h * HDIM);
    const float4* qp = (const float4*)(qkv + (size_t)d * D3 + h * HDIM);
    float acc = 0.0f;
    #pragma unroll
    for (int i = 0; i < 8; ++i) {
        float4 kv = kp[i], qv = qp[i];
        acc += kv.x * qv.x + kv.y * qv.y + kv.z * qv.z + kv.w * qv.w;
    }
    bool valid = (nmask[s] != 0.0f) && (nmask[d] != 0.0f);
    scores[idx] = valid ? acc : -10000.0f;
}

// ---------------- CSR build: histogram / scan / scatter ----------------
__global__ void hist_kernel(const int* __restrict__ dst, int* __restrict__ deg) {
    int e = blockIdx.x * 256 + threadIdx.x;
    atomicAdd(&deg[dst[e]], 1);
}

__global__ __launch_bounds__(1024) void scan_kernel(const int* __restrict__ deg,
                                                    int* __restrict__ offs,
                                                    int* __restrict__ cursor, int n) {
    __shared__ int part[1024];
    int t = threadIdx.x;
    int base = t * 16;
    int local[16];
    int s = 0;
    #pragma unroll
    for (int i = 0; i < 16; ++i) { local[i] = s; s += deg[base + i]; }
    part[t] = s;
    __syncthreads();
    for (int d = 1; d < 1024; d <<= 1) {
        int add = (t >= d) ? part[t - d] : 0;
        __syncthreads();
        part[t] += add;
        __syncthreads();
    }
    int excl = part[t] - s;
    #pragma unroll
    for (int i = 0; i < 16; ++i) {
        offs[base + i] = excl + local[i];
        cursor[base + i] = excl + local[i];
    }
    if (t == 1023) offs[n] = excl + s;
}

__global__ void scatter_kernel(const int* __restrict__ dst, int* __restrict__ cursor,
                               int* __restrict__ elist) {
    int e = blockIdx.x * 256 + threadIdx.x;
    int pos = atomicAdd(&cursor[dst[e]], 1);
    elist[pos] = e;
}

// ---------------- per-(node,head) segment softmax, in place on scores ----------------
__global__ void softmax_kernel(const int* __restrict__ offs, const int* __restrict__ elist,
                               float* __restrict__ attn) {
    int gid = blockIdx.x * 256 + threadIdx.x;   // node*8 + h
    int node = gid >> 3, h = gid & 7;
    int beg = offs[node], end = offs[node + 1];
    if (beg == end) return;
    float m = -INFINITY;
    for (int i = beg; i < end; ++i) {
        int e = elist[i];
        m = fmaxf(m, attn[e * 8 + h]);
    }
    float den = 0.0f;
    for (int i = beg; i < end; ++i) {
        int e = elist[i];
        den += __expf(attn[e * 8 + h] - m);
    }
    float inv = 1.0f / den;
    for (int i = beg; i < end; ++i) {
        int e = elist[i];
        attn[e * 8 + h] = __expf(attn[e * 8 + h] - m) * inv;
    }
}

// ---------------- h0 = exp(-1) * v ; gather = h0 ----------------
__global__ void init_h_kernel(const float* __restrict__ qkv, float* __restrict__ hA,
                              float* __restrict__ gather) {
    int i = blockIdx.x * 256 + threadIdx.x;     // float4 index, NN*64 total
    int n = i >> 6;
    int c4 = (i & 63) * 4;
    float4 v = *(const float4*)(qkv + (size_t)n * D3 + 2 * DD + c4);
    float4 r;
    r.x = v.x * EXPN1; r.y = v.y * EXPN1; r.z = v.z * EXPN1; r.w = v.w * EXPN1;
    *(float4*)(hA + (size_t)n * DD + c4) = r;
    *(float4*)(gather + (size_t)n * DD + c4) = r;
}

// ---------------- one diffusion step: hnext = segsum(attn * hcur[src]); gather += fact*hnext ----
__global__ void diffuse_kernel(const int* __restrict__ offs, const int* __restrict__ elist,
                               const int* __restrict__ src, const float* __restrict__ attn,
                               const float* __restrict__ hcur, float* __restrict__ hnext,
                               float* __restrict__ gather, float fact) {
    int gid = blockIdx.x * 256 + threadIdx.x;   // node*256 + h*32 + c
    int c = gid & 31;
    int h = (gid >> 5) & 7;
    int node = gid >> 8;
    int beg = offs[node], end = offs[node + 1];
    float acc = 0.0f;
    for (int i = beg; i < end; ++i) {
        int e = elist[i];
        int s = src[e];
        acc += attn[e * 8 + h] * hcur[(size_t)s * DD + h * HDIM + c];
    }
    size_t o = (size_t)node * DD + h * HDIM + c;
    hnext[o] = acc;
    gather[o] += fact * acc;
}

// ---------------- LayerNorm, one wave per row ----------------
__global__ __launch_bounds__(256) void ln_kernel(const float* __restrict__ y,
                                                 const float* __restrict__ gamma,
                                                 const float* __restrict__ beta,
                                                 float* __restrict__ out) {
    int wave = threadIdx.x >> 6;
    int lane = threadIdx.x & 63;
    int row = blockIdx.x * 4 + wave;
    const float* yr = y + (size_t)row * DD;
    float4 v = *(const float4*)(yr + lane * 4);
    float s = v.x + v.y + v.z + v.w;
    #pragma unroll
    for (int m = 32; m >= 1; m >>= 1) s += __shfl_xor(s, m);
    float mu = s * (1.0f / 256.0f);
    float dx = v.x - mu, dy = v.y - mu, dz = v.z - mu, dw = v.w - mu;
    float sq = dx * dx + dy * dy + dz * dz + dw * dw;
    #pragma unroll
    for (int m = 32; m >= 1; m >>= 1) sq += __shfl_xor(sq, m);
    float var = sq * (1.0f / 256.0f);
    float rstd = 1.0f / sqrtf(var + LN_EPS);
    float4 g = *(const float4*)(gamma + lane * 4);
    float4 b = *(const float4*)(beta + lane * 4);
    float4 o;
    o.x = dx * rstd * g.x + b.x;
    o.y = dy * rstd * g.y + b.y;
    o.z = dz * rstd * g.z + b.z;
    o.w = dw * rstd * g.w + b.w;
    *(float4*)(out + (size_t)row * DD + lane * 4) = o;
}

extern "C" void kernel_launch(void* const* d_in, const int* in_sizes, int n_in,
                              void* d_out, int out_size, void* d_ws, size_t ws_size,
                              hipStream_t stream) {
    const float* hidden = (const float*)d_in[0];
    const float* amask  = (const float*)d_in[1];
    const int*   src    = (const int*)d_in[2];
    const int*   dst    = (const int*)d_in[3];
    const float* Wqkv   = (const float*)d_in[4];
    const float* bqkv   = (const float*)d_in[5];
    const float* Wo     = (const float*)d_in[6];
    const float* bo     = (const float*)d_in[7];
    const float* gamma  = (const float*)d_in[8];
    const float* beta   = (const float*)d_in[9];
    float* out = (float*)d_out;

    char* p = (char*)d_ws;
    float* qkv    = (float*)p; p += (size_t)NN * D3 * 4;       // 48 MB
    float* attn   = (float*)p; p += (size_t)EE * HH * 4;       // 8 MB
    float* hA     = (float*)p; p += (size_t)NN * DD * 4;       // 16 MB
    float* hB     = (float*)p; p += (size_t)NN * DD * 4;       // 16 MB
    float* gather = (float*)p; p += (size_t)NN * DD * 4;       // 16 MB
    float* nmask  = (float*)p; p += (size_t)NN * 4;
    int*   deg    = (int*)p;   p += (size_t)NN * 4;
    int*   offs   = (int*)p;   p += (size_t)(NN + 1) * 4;
    int*   cursor = (int*)p;   p += (size_t)NN * 4;
    int*   elist  = (int*)p;   p += (size_t)EE * 4;
    float* y      = hA;  // reuse: hA is free after the 3rd diffuse step

    // 1. node mask
    node_mask_kernel<<<NN / 256, 256, 0, stream>>>(amask, nmask);

    // 2. QKV projection (q columns pre-scaled by 1/sqrt(HD))
    gemm_kernel<<<dim3(D3 / 64, NN / 64), 256, 0, stream>>>(
        hidden, Wqkv, bqkv, nullptr, qkv, NN, D3, DD, DD, QSCALE);

    // 3. edge scores
    edge_score_kernel<<<(EE * HH) / 256, 256, 0, stream>>>(qkv, src, dst, nmask, attn);

    // 4. CSR build over dst
    hipMemsetAsync(deg, 0, (size_t)NN * 4, stream);
    hist_kernel<<<EE / 256, 256, 0, stream>>>(dst, deg);
    scan_kernel<<<1, 1024, 0, stream>>>(deg, offs, cursor, NN);
    scatter_kernel<<<EE / 256, 256, 0, stream>>>(dst, cursor, elist);

    // 5. segment softmax (in place on attn)
    softmax_kernel<<<(NN * HH) / 256, 256, 0, stream>>>(offs, elist, attn);

    // 6. h0 and gather init
    init_h_kernel<<<(NN * DD / 4) / 256, 256, 0, stream>>>(qkv, hA, gather);

    // 7. diffusion: gather = h0 + h1 + h2/2 + h3/6
    diffuse_kernel<<<(NN * DD) / 256, 256, 0, stream>>>(offs, elist, src, attn, hA, hB, gather, 1.0f);
    diffuse_kernel<<<(NN * DD) / 256, 256, 0, stream>>>(offs, elist, src, attn, hB, hA, gather, 0.5f);
    diffuse_kernel<<<(NN * DD) / 256, 256, 0, stream>>>(offs, elist, src, attn, hA, hB, gather, 1.0f / 6.0f);

    // 8. output projection + residual (writes into hA, which is free now)
    gemm_kernel<<<dim3(DD / 64, NN / 64), 256, 0, stream>>>(
        gather, Wo, bo, hidden, y, NN, DD, DD, 0, 1.0f);

    // 9. LayerNorm
    ln_kernel<<<NN / 4, 256, 0, stream>>>(y, gamma, beta, out);
}

// Round 2
// 477.569 us; speedup vs baseline: 1.6148x; 1.6148x over previous
//
#include <hip/hip_runtime.h>
#include <math.h>

#define NN 16384      // B*S nodes
#define DD 256        // model dim
#define HH 8          // heads
#define HDIM 32       // head dim
#define EE 262144     // edges
#define D3 768        // 3*D
#define QSCALE 0.17677669529663687f   // 1/sqrt(32)
#define EXPN1 0.36787944117144233f    // exp(-1)
#define LN_EPS 1e-12f

// ---- bf16 helpers (bit tricks; no lib conversions) ----
__device__ __forceinline__ float bf_lo(unsigned u) { return __uint_as_float(u << 16); }
__device__ __forceinline__ float bf_hi(unsigned u) { return __uint_as_float(u & 0xffff0000u); }
__device__ __forceinline__ unsigned f2bf(float f) {  // round-nearest-even, returns in low 16
    unsigned b = __float_as_uint(f);
    return (b + 0x7fffu + ((b >> 16) & 1u)) >> 16;
}
__device__ __forceinline__ unsigned pack2bf(float lo, float hi) {
    return f2bf(lo) | (f2bf(hi) << 16);
}

// ---------------- node mask ----------------
__global__ void node_mask_kernel(const float* __restrict__ am, float* __restrict__ nmask) {
    int i = blockIdx.x * 256 + threadIdx.x;
    nmask[i] = (am[i] >= 0.0f) ? 1.0f : 0.0f;
}

// ---------------- tiled fp32 GEMM: C = A[M,K] @ B[K,Nc] + bias (+resid), q-scale on first scale_cols ----
__global__ __launch_bounds__(256) void gemm_kernel(
        const float* __restrict__ A, const float* __restrict__ B,
        const float* __restrict__ bias, const float* __restrict__ resid,
        float* __restrict__ C, int M, int Nc, int K,
        int scale_cols, float scale) {
    __shared__ float As[16][68];
    __shared__ float Bs[16][68];
    const int tid = threadIdx.x;
    const int tx = tid & 15, ty = tid >> 4;
    const int row0 = blockIdx.y * 64;
    const int col0 = blockIdx.x * 64;
    float acc[4][4] = {};
    for (int k0 = 0; k0 < K; k0 += 16) {
        {
            int r = tid >> 2;
            int kk = (tid & 3) * 4;
            float4 av = *(const float4*)(A + (size_t)(row0 + r) * K + k0 + kk);
            As[kk + 0][r] = av.x; As[kk + 1][r] = av.y;
            As[kk + 2][r] = av.z; As[kk + 3][r] = av.w;
        }
        {
            int kk = tid >> 4;
            int c = (tid & 15) * 4;
            float4 bv = *(const float4*)(B + (size_t)(k0 + kk) * Nc + col0 + c);
            *(float4*)&Bs[kk][c] = bv;
        }
        __syncthreads();
        #pragma unroll
        for (int k = 0; k < 16; ++k) {
            float4 a4 = *(const float4*)&As[k][ty * 4];
            float4 b4 = *(const float4*)&Bs[k][tx * 4];
            float av[4] = {a4.x, a4.y, a4.z, a4.w};
            float bv[4] = {b4.x, b4.y, b4.z, b4.w};
            #pragma unroll
            for (int i = 0; i < 4; ++i)
                #pragma unroll
                for (int j = 0; j < 4; ++j)
                    acc[i][j] += av[i] * bv[j];
        }
        __syncthreads();
    }
    #pragma unroll
    for (int i = 0; i < 4; ++i) {
        int r = row0 + ty * 4 + i;
        #pragma unroll
        for (int j = 0; j < 4; ++j) {
            int c = col0 + tx * 4 + j;
            float v = acc[i][j] + bias[c];
            if (c < scale_cols) v *= scale;
            if (resid) v += resid[(size_t)r * Nc + c];
            C[(size_t)r * Nc + c] = v;
        }
    }
}

// ---------------- CSR build: histogram / scan / scatter (store e->pos) ----------------
__global__ void hist_kernel(const int* __restrict__ dst, int* __restrict__ deg) {
    int e = blockIdx.x * 256 + threadIdx.x;
    atomicAdd(&deg[dst[e]], 1);
}

__global__ __launch_bounds__(1024) void scan_kernel(const int* __restrict__ deg,
                                                    int* __restrict__ offs,
                                                    int* __restrict__ cursor, int n) {
    __shared__ int part[1024];
    int t = threadIdx.x;
    int base = t * 16;
    int local[16];
    int s = 0;
    #pragma unroll
    for (int i = 0; i < 16; ++i) { local[i] = s; s += deg[base + i]; }
    part[t] = s;
    __syncthreads();
    for (int d = 1; d < 1024; d <<= 1) {
        int add = (t >= d) ? part[t - d] : 0;
        __syncthreads();
        part[t] += add;
        __syncthreads();
    }
    int excl = part[t] - s;
    #pragma unroll
    for (int i = 0; i < 16; ++i) {
        offs[base + i] = excl + local[i];
        cursor[base + i] = excl + local[i];
    }
    if (t == 1023) offs[n] = excl + s;
}

__global__ void scatter_kernel(const int* __restrict__ dst, int* __restrict__ cursor,
                               int* __restrict__ epos) {
    int e = blockIdx.x * 256 + threadIdx.x;
    epos[e] = atomicAdd(&cursor[dst[e]], 1);
}

// ---------------- prep: qkv fp32 -> qb/kb/h0 bf16-packed, gather fp32 init ----------------
// thread per (node, j) j=0..127, channels (2j, 2j+1)
__global__ void prep_kernel(const float* __restrict__ qkv,
                            unsigned* __restrict__ qb, unsigned* __restrict__ kb,
                            unsigned* __restrict__ h0, float* __restrict__ gather) {
    int gid = blockIdx.x * 256 + threadIdx.x;
    int n = gid >> 7;
    int j = gid & 127;
    const float* row = qkv + (size_t)n * D3;
    float2 q = *(const float2*)(row + 2 * j);
    float2 k = *(const float2*)(row + DD + 2 * j);
    float2 v = *(const float2*)(row + 2 * DD + 2 * j);
    size_t o = (size_t)n * 128 + j;
    qb[o] = pack2bf(q.x, q.y);
    kb[o] = pack2bf(k.x, k.y);
    float hx = v.x * EXPN1, hy = v.y * EXPN1;
    h0[o] = pack2bf(hx, hy);
    *(float2*)(gather + (size_t)n * DD + 2 * j) = make_float2(hx, hy);
}

// ---------------- per-(edge,head) scores -> CSR position ----------------
__global__ void edge_score_kernel(const unsigned* __restrict__ qb, const unsigned* __restrict__ kb,
                                  const int* __restrict__ src, const int* __restrict__ dst,
                                  const int* __restrict__ epos, const float* __restrict__ nmask,
                                  float* __restrict__ attn, int* __restrict__ srcs) {
    int idx = blockIdx.x * 256 + threadIdx.x;   // e*8 + h
    int e = idx >> 3, h = idx & 7;
    int s = src[e], d = dst[e];
    int pos = epos[e];
    const uint4* kp = (const uint4*)(kb + (size_t)s * 128 + h * 16);
    const uint4* qp = (const uint4*)(qb + (size_t)d * 128 + h * 16);
    float acc = 0.0f;
    #pragma unroll
    for (int i = 0; i < 4; ++i) {
        uint4 kv = kp[i], qv = qp[i];
        acc += bf_lo(kv.x) * bf_lo(qv.x) + bf_hi(kv.x) * bf_hi(qv.x);
        acc += bf_lo(kv.y) * bf_lo(qv.y) + bf_hi(kv.y) * bf_hi(qv.y);
        acc += bf_lo(kv.z) * bf_lo(qv.z) + bf_hi(kv.z) * bf_hi(qv.z);
        acc += bf_lo(kv.w) * bf_lo(qv.w) + bf_hi(kv.w) * bf_hi(qv.w);
    }
    bool valid = (nmask[s] != 0.0f) && (nmask[d] != 0.0f);
    attn[(size_t)pos * 8 + h] = valid ? acc : -10000.0f;
    if (h == 0) srcs[pos] = s;
}

// ---------------- per-(node,head) segment softmax, contiguous CSR ----------------
__global__ void softmax_kernel(const int* __restrict__ offs, float* __restrict__ attn) {
    int gid = blockIdx.x * 256 + threadIdx.x;   // node*8 + h
    int node = gid >> 3, h = gid & 7;
    int beg = offs[node], end = offs[node + 1];
    if (beg == end) return;
    float m = -INFINITY;
    for (int i = beg; i < end; ++i) m = fmaxf(m, attn[(size_t)i * 8 + h]);
    float den = 0.0f;
    for (int i = beg; i < end; ++i) {
        float es = __expf(attn[(size_t)i * 8 + h] - m);
        attn[(size_t)i * 8 + h] = es;
        den += es;
    }
    float inv = 1.0f / den;
    for (int i = beg; i < end; ++i) attn[(size_t)i * 8 + h] *= inv;
}

// ---------------- one diffusion step (bf16 h): hnext = segsum(attn * h[src]); gather += fact*hnext ----
// thread per (node, j) j=0..127: channels (2j, 2j+1), head h = j>>4
__global__ void diffuse_kernel(const int* __restrict__ offs, const int* __restrict__ srcs,
                               const float* __restrict__ attn,
                               const unsigned* __restrict__ hcur, unsigned* __restrict__ hnext,
                               float* __restrict__ gather, float fact) {
    int gid = blockIdx.x * 256 + threadIdx.x;
    int node = gid >> 7;
    int j = gid & 127;
    int h = j >> 4;
    int beg = offs[node], end = offs[node + 1];
    float ax = 0.0f, ay = 0.0f;
    for (int i = beg; i < end; ++i) {
        int s = srcs[i];
        float a = attn[(size_t)i * 8 + h];
        unsigned hv = hcur[(size_t)s * 128 + j];
        ax += a * bf_lo(hv);
        ay += a * bf_hi(hv);
    }
    hnext[(size_t)node * 128 + j] = pack2bf(ax, ay);
    float2* gp = (float2*)(gather + (size_t)node * DD + 2 * j);
    float2 g = *gp;
    g.x += fact * ax; g.y += fact * ay;
    *gp = g;
}

// ---------------- LayerNorm, one wave per row ----------------
__global__ __launch_bounds__(256) void ln_kernel(const float* __restrict__ y,
                                                 const float* __restrict__ gamma,
                                                 const float* __restrict__ beta,
                                                 float* __restrict__ out) {
    int wave = threadIdx.x >> 6;
    int lane = threadIdx.x & 63;
    int row = blockIdx.x * 4 + wave;
    const float* yr = y + (size_t)row * DD;
    float4 v = *(const float4*)(yr + lane * 4);
    float s = v.x + v.y + v.z + v.w;
    #pragma unroll
    for (int m = 32; m >= 1; m >>= 1) s += __shfl_xor(s, m);
    float mu = s * (1.0f / 256.0f);
    float dx = v.x - mu, dy = v.y - mu, dz = v.z - mu, dw = v.w - mu;
    float sq = dx * dx + dy * dy + dz * dz + dw * dw;
    #pragma unroll
    for (int m = 32; m >= 1; m >>= 1) sq += __shfl_xor(sq, m);
    float var = sq * (1.0f / 256.0f);
    float rstd = 1.0f / sqrtf(var + LN_EPS);
    float4 g = *(const float4*)(gamma + lane * 4);
    float4 b = *(const float4*)(beta + lane * 4);
    float4 o;
    o.x = dx * rstd * g.x + b.x;
    o.y = dy * rstd * g.y + b.y;
    o.z = dz * rstd * g.z + b.z;
    o.w = dw * rstd * g.w + b.w;
    *(float4*)(out + (size_t)row * DD + lane * 4) = o;
}

extern "C" void kernel_launch(void* const* d_in, const int* in_sizes, int n_in,
                              void* d_out, int out_size, void* d_ws, size_t ws_size,
                              hipStream_t stream) {
    const float* hidden = (const float*)d_in[0];
    const float* amask  = (const float*)d_in[1];
    const int*   src    = (const int*)d_in[2];
    const int*   dst    = (const int*)d_in[3];
    const float* Wqkv   = (const float*)d_in[4];
    const float* bqkv   = (const float*)d_in[5];
    const float* Wo     = (const float*)d_in[6];
    const float* bo     = (const float*)d_in[7];
    const float* gamma  = (const float*)d_in[8];
    const float* beta   = (const float*)d_in[9];
    float* out = (float*)d_out;

    char* p = (char*)d_ws;
    float*    qkv    = (float*)p;    p += (size_t)NN * D3 * 4;   // 48 MB (freed after prep; y aliases)
    float*    attn   = (float*)p;    p += (size_t)EE * HH * 4;   // 8 MB
    unsigned* qb     = (unsigned*)p; p += (size_t)NN * 128 * 4;  // 8 MB bf16-packed
    unsigned* kb     = (unsigned*)p; p += (size_t)NN * 128 * 4;  // 8 MB
    unsigned* hA     = (unsigned*)p; p += (size_t)NN * 128 * 4;  // 8 MB
    unsigned* hB     = (unsigned*)p; p += (size_t)NN * 128 * 4;  // 8 MB
    float*    gather = (float*)p;    p += (size_t)NN * DD * 4;   // 16 MB
    float*    nmask  = (float*)p;    p += (size_t)NN * 4;
    int*      deg    = (int*)p;      p += (size_t)NN * 4;
    int*      offs   = (int*)p;      p += (size_t)(NN + 1) * 4;
    int*      cursor = (int*)p;      p += (size_t)NN * 4;
    int*      epos   = (int*)p;      p += (size_t)EE * 4;        // 1 MB
    int*      srcs   = (int*)p;      p += (size_t)EE * 4;        // 1 MB
    float*    y      = qkv;  // alias: qkv dead after prep_kernel

    // 1. node mask
    node_mask_kernel<<<NN / 256, 256, 0, stream>>>(amask, nmask);

    // 2. QKV projection (q columns pre-scaled by 1/sqrt(HD))
    gemm_kernel<<<dim3(D3 / 64, NN / 64), 256, 0, stream>>>(
        hidden, Wqkv, bqkv, nullptr, qkv, NN, D3, DD, DD, QSCALE);

    // 3. CSR build over dst (independent of gemm; epos maps edge -> csr slot)
    hipMemsetAsync(deg, 0, (size_t)NN * 4, stream);
    hist_kernel<<<EE / 256, 256, 0, stream>>>(dst, deg);
    scan_kernel<<<1, 1024, 0, stream>>>(deg, offs, cursor, NN);
    scatter_kernel<<<EE / 256, 256, 0, stream>>>(dst, cursor, epos);

    // 4. bf16 packing + h0/gather init
    prep_kernel<<<(NN * 128) / 256, 256, 0, stream>>>(qkv, qb, kb, hA, gather);

    // 5. edge scores, written in CSR order (srcs permuted alongside)
    edge_score_kernel<<<(EE * HH) / 256, 256, 0, stream>>>(qb, kb, src, dst, epos, nmask, attn, srcs);

    // 6. segment softmax (in place, contiguous per node)
    softmax_kernel<<<(NN * HH) / 256, 256, 0, stream>>>(offs, attn);

    // 7. diffusion: gather = h0 + h1 + h2/2 + h3/6
    diffuse_kernel<<<(NN * 128) / 256, 256, 0, stream>>>(offs, srcs, attn, hA, hB, gather, 1.0f);
    diffuse_kernel<<<(NN * 128) / 256, 256, 0, stream>>>(offs, srcs, attn, hB, hA, gather, 0.5f);
    diffuse_kernel<<<(NN * 128) / 256, 256, 0, stream>>>(offs, srcs, attn, hA, hB, gather, 1.0f / 6.0f);

    // 8. output projection + residual (into y, aliasing qkv)
    gemm_kernel<<<dim3(DD / 64, NN / 64), 256, 0, stream>>>(
        gather, Wo, bo, hidden, y, NN, DD, DD, 0, 1.0f);

    // 9. LayerNorm
    ln_kernel<<<NN / 4, 256, 0, stream>>>(y, gamma, beta, out);
}

// Round 3
// 385.958 us; speedup vs baseline: 1.9980x; 1.2374x over previous
//
#include <hip/hip_runtime.h>
#include <math.h>

#define NN 16384      // B*S nodes
#define DD 256        // model dim
#define HH 8          // heads
#define HDIM 32       // head dim
#define EE 262144     // edges
#define D3 768        // 3*D
#define QSCALE 0.17677669529663687f   // 1/sqrt(32)
#define EXPN1 0.36787944117144233f    // exp(-1)
#define LN_EPS 1e-12f

typedef short bf16x8 __attribute__((ext_vector_type(8)));
typedef float f32x4 __attribute__((ext_vector_type(4)));
typedef unsigned short u16;

// ---- bf16 helpers (bit tricks) ----
__device__ __forceinline__ float bf_lo(unsigned u) { return __uint_as_float(u << 16); }
__device__ __forceinline__ float bf_hi(unsigned u) { return __uint_as_float(u & 0xffff0000u); }
__device__ __forceinline__ unsigned f2bf(float f) {  // RNE, result in low 16
    unsigned b = __float_as_uint(f);
    return (b + 0x7fffu + ((b >> 16) & 1u)) >> 16;
}
__device__ __forceinline__ unsigned pack2bf(float lo, float hi) {
    return f2bf(lo) | (f2bf(hi) << 16);
}

// ---------------- node mask ----------------
__global__ void node_mask_kernel(const float* __restrict__ am, float* __restrict__ nmask) {
    int i = blockIdx.x * 256 + threadIdx.x;
    nmask[i] = (am[i] >= 0.0f) ? 1.0f : 0.0f;
}

// ---------------- hidden fp32 -> bf16 ----------------
__global__ void hconv_kernel(const float* __restrict__ x, unsigned* __restrict__ xb) {
    int gid = blockIdx.x * 256 + threadIdx.x;   // one per 4 floats
    float4 v = *(const float4*)(x + (size_t)gid * 4);
    uint2 o;
    o.x = pack2bf(v.x, v.y);
    o.y = pack2bf(v.z, v.w);
    *(uint2*)(xb + (size_t)gid * 2) = o;
}

// ---------------- weight transpose + bf16 (+ q-scale fold + scaled bias) ----------------
// W [K=256][Nw] -> Wt [Nw][256] bf16 ; scale applied to cols n < scale_cols
__global__ void wconv_kernel(const float* __restrict__ W, const float* __restrict__ b,
                             u16* __restrict__ Wt, float* __restrict__ bias_s,
                             int Nw, int scale_cols) {
    int gid = blockIdx.x * 256 + threadIdx.x;   // n*256 + k
    int n = gid >> 8, k = gid & 255;
    float s = (n < scale_cols) ? QSCALE : 1.0f;
    Wt[(size_t)n * 256 + k] = (u16)f2bf(W[(size_t)k * Nw + n] * s);
    if (k == 0) bias_s[n] = b[n] * s;
}

// ---------------- MFMA GEMM: C[M,Nc] = Abf[M,256] @ Bt[Nc,256]^T + bias ----------------
// 128x128 tile, 4 waves (2x2), 4x4 16x16x32 frags per wave, K=256.
// MODE 0: qkv epilogue (n0>>8 selects q/k/v target). MODE 1: out-proj (+resid -> y).
template <int MODE>
__global__ __launch_bounds__(256) void mfma_gemm_kernel(
        const u16* __restrict__ Ab, const u16* __restrict__ Bt,
        const float* __restrict__ bias,
        u16* __restrict__ qb, u16* __restrict__ kb,
        u16* __restrict__ hA, float* __restrict__ gather,
        const float* __restrict__ resid, float* __restrict__ y) {
    __shared__ u16 As[128 * 40];
    __shared__ u16 Bs[128 * 40];
    const int tid = threadIdx.x;
    const int m0 = blockIdx.y * 128;
    const int n0 = blockIdx.x * 128;
    const int wave = tid >> 6, lane = tid & 63;
    const int wr = wave >> 1, wc = wave & 1;
    const int lm = lane & 15, quad = lane >> 4;

    f32x4 acc[4][4] = {};

    const int r0 = tid >> 2;             // 0..63
    const int c8 = (tid & 3) * 8;        // 0,8,16,24

    for (int k0 = 0; k0 < 256; k0 += 32) {
        #pragma unroll
        for (int s = 0; s < 2; ++s) {
            int r = r0 + s * 64;
            *(uint4*)&As[r * 40 + c8] = *(const uint4*)(Ab + (size_t)(m0 + r) * 256 + k0 + c8);
            *(uint4*)&Bs[r * 40 + c8] = *(const uint4*)(Bt + (size_t)(n0 + r) * 256 + k0 + c8);
        }
        __syncthreads();
        bf16x8 af[4], bfv[4];
        #pragma unroll
        for (int mi = 0; mi < 4; ++mi)
            af[mi] = *(const bf16x8*)&As[(wr * 64 + mi * 16 + lm) * 40 + quad * 8];
        #pragma unroll
        for (int ni = 0; ni < 4; ++ni)
            bfv[ni] = *(const bf16x8*)&Bs[(wc * 64 + ni * 16 + lm) * 40 + quad * 8];
        #pragma unroll
        for (int mi = 0; mi < 4; ++mi)
            #pragma unroll
            for (int ni = 0; ni < 4; ++ni)
                acc[mi][ni] = __builtin_amdgcn_mfma_f32_16x16x32_bf16(
                    af[mi], bfv[ni], acc[mi][ni], 0, 0, 0);
        __syncthreads();
    }

    // epilogue: C row m = m0 + wr*64 + mi*16 + quad*4 + j ; col nl = wc*64 + ni*16 + lm
    if (MODE == 0) {
        const int type = n0 >> 8;        // 0=q 1=k 2=v
        const int cb = n0 & 255;
        #pragma unroll
        for (int mi = 0; mi < 4; ++mi) {
            #pragma unroll
            for (int j = 0; j < 4; ++j) {
                int m = m0 + wr * 64 + mi * 16 + quad * 4 + j;
                #pragma unroll
                for (int ni = 0; ni < 4; ++ni) {
                    int nl = wc * 64 + ni * 16 + lm;
                    float val = acc[mi][ni][j] + bias[n0 + nl];
                    size_t off = (size_t)m * 256 + cb + nl;
                    if (type == 0) qb[off] = (u16)f2bf(val);
                    else if (type == 1) kb[off] = (u16)f2bf(val);
                    else {
                        float hx = val * EXPN1;
                        hA[off] = (u16)f2bf(hx);
                        gather[off] = hx;
                    }
                }
            }
        }
    } else {
        #pragma unroll
        for (int mi = 0; mi < 4; ++mi) {
            #pragma unroll
            for (int j = 0; j < 4; ++j) {
                int m = m0 + wr * 64 + mi * 16 + quad * 4 + j;
                #pragma unroll
                for (int ni = 0; ni < 4; ++ni) {
                    int nl = wc * 64 + ni * 16 + lm;
                    size_t off = (size_t)m * 256 + n0 + nl;
                    y[off] = acc[mi][ni][j] + bias[n0 + nl] + resid[off];
                }
            }
        }
    }
}

// ---------------- CSR build: histogram / scan / scatter (store e->pos) ----------------
__global__ void hist_kernel(const int* __restrict__ dst, int* __restrict__ deg) {
    int e = blockIdx.x * 256 + threadIdx.x;
    atomicAdd(&deg[dst[e]], 1);
}

__global__ __launch_bounds__(1024) void scan_kernel(const int* __restrict__ deg,
                                                    int* __restrict__ offs,
                                                    int* __restrict__ cursor, int n) {
    __shared__ int part[1024];
    int t = threadIdx.x;
    int base = t * 16;
    int local[16];
    int s = 0;
    #pragma unroll
    for (int i = 0; i < 16; ++i) { local[i] = s; s += deg[base + i]; }
    part[t] = s;
    __syncthreads();
    for (int d = 1; d < 1024; d <<= 1) {
        int add = (t >= d) ? part[t - d] : 0;
        __syncthreads();
        part[t] += add;
        __syncthreads();
    }
    int excl = part[t] - s;
    #pragma unroll
    for (int i = 0; i < 16; ++i) {
        offs[base + i] = excl + local[i];
        cursor[base + i] = excl + local[i];
    }
    if (t == 1023) offs[n] = excl + s;
}

__global__ void scatter_kernel(const int* __restrict__ dst, int* __restrict__ cursor,
                               int* __restrict__ epos) {
    int e = blockIdx.x * 256 + threadIdx.x;
    epos[e] = atomicAdd(&cursor[dst[e]], 1);
}

// ---------------- per-(edge,head) scores -> CSR position ----------------
__global__ void edge_score_kernel(const unsigned* __restrict__ qb, const unsigned* __restrict__ kb,
                                  const int* __restrict__ src, const int* __restrict__ dst,
                                  const int* __restrict__ epos, const float* __restrict__ nmask,
                                  float* __restrict__ attn, int* __restrict__ srcs) {
    int idx = blockIdx.x * 256 + threadIdx.x;   // e*8 + h
    int e = idx >> 3, h = idx & 7;
    int s = src[e], d = dst[e];
    int pos = epos[e];
    const uint4* kp = (const uint4*)(kb + (size_t)s * 128 + h * 16);
    const uint4* qp = (const uint4*)(qb + (size_t)d * 128 + h * 16);
    float acc = 0.0f;
    #pragma unroll
    for (int i = 0; i < 4; ++i) {
        uint4 kv = kp[i], qv = qp[i];
        acc += bf_lo(kv.x) * bf_lo(qv.x) + bf_hi(kv.x) * bf_hi(qv.x);
        acc += bf_lo(kv.y) * bf_lo(qv.y) + bf_hi(kv.y) * bf_hi(qv.y);
        acc += bf_lo(kv.z) * bf_lo(qv.z) + bf_hi(kv.z) * bf_hi(qv.z);
        acc += bf_lo(kv.w) * bf_lo(qv.w) + bf_hi(kv.w) * bf_hi(qv.w);
    }
    bool valid = (nmask[s] != 0.0f) && (nmask[d] != 0.0f);
    attn[(size_t)pos * 8 + h] = valid ? acc : -10000.0f;
    if (h == 0) srcs[pos] = s;
}

// ---------------- per-(node,head) segment softmax, contiguous CSR ----------------
__global__ void softmax_kernel(const int* __restrict__ offs, float* __restrict__ attn) {
    int gid = blockIdx.x * 256 + threadIdx.x;   // node*8 + h
    int node = gid >> 3, h = gid & 7;
    int beg = offs[node], end = offs[node + 1];
    if (beg == end) return;
    float m = -INFINITY;
    for (int i = beg; i < end; ++i) m = fmaxf(m, attn[(size_t)i * 8 + h]);
    float den = 0.0f;
    for (int i = beg; i < end; ++i) {
        float es = __expf(attn[(size_t)i * 8 + h] - m);
        attn[(size_t)i * 8 + h] = es;
        den += es;
    }
    float inv = 1.0f / den;
    for (int i = beg; i < end; ++i) attn[(size_t)i * 8 + h] *= inv;
}

// ---------------- one diffusion step (bf16 h) ----------------
// thread per (node, j) j=0..127: channels (2j,2j+1), head h = j>>4.
// hnext (nullable): packed bf16 of segsum. gout (nullable): final bf16 gather.
__global__ void diffuse_kernel(const int* __restrict__ offs, const int* __restrict__ srcs,
                               const float* __restrict__ attn,
                               const unsigned* __restrict__ hcur, unsigned* __restrict__ hnext,
                               float* __restrict__ gather, unsigned* __restrict__ gout,
                               float fact) {
    int gid = blockIdx.x * 256 + threadIdx.x;
    int node = gid >> 7;
    int j = gid & 127;
    int h = j >> 4;
    int beg = offs[node], end = offs[node + 1];
    float ax = 0.0f, ay = 0.0f;
    for (int i = beg; i < end; ++i) {
        int s = srcs[i];
        float a = attn[(size_t)i * 8 + h];
        unsigned hv = hcur[(size_t)s * 128 + j];
        ax += a * bf_lo(hv);
        ay += a * bf_hi(hv);
    }
    if (hnext) hnext[(size_t)node * 128 + j] = pack2bf(ax, ay);
    float2* gp = (float2*)(gather + (size_t)node * DD + 2 * j);
    float2 g = *gp;
    g.x += fact * ax; g.y += fact * ay;
    if (gout) gout[(size_t)node * 128 + j] = pack2bf(g.x, g.y);
    else *gp = g;
}

// ---------------- LayerNorm, one wave per row ----------------
__global__ __launch_bounds__(256) void ln_kernel(const float* __restrict__ y,
                                                 const float* __restrict__ gamma,
                                                 const float* __restrict__ beta,
                                                 float* __restrict__ out) {
    int wave = threadIdx.x >> 6;
    int lane = threadIdx.x & 63;
    int row = blockIdx.x * 4 + wave;
    const float* yr = y + (size_t)row * DD;
    float4 v = *(const float4*)(yr + lane * 4);
    float s = v.x + v.y + v.z + v.w;
    #pragma unroll
    for (int m = 32; m >= 1; m >>= 1) s += __shfl_xor(s, m);
    float mu = s * (1.0f / 256.0f);
    float dx = v.x - mu, dy = v.y - mu, dz = v.z - mu, dw = v.w - mu;
    float sq = dx * dx + dy * dy + dz * dz + dw * dw;
    #pragma unroll
    for (int m = 32; m >= 1; m >>= 1) sq += __shfl_xor(sq, m);
    float var = sq * (1.0f / 256.0f);
    float rstd = 1.0f / sqrtf(var + LN_EPS);
    float4 g = *(const float4*)(gamma + lane * 4);
    float4 b = *(const float4*)(beta + lane * 4);
    float4 o;
    o.x = dx * rstd * g.x + b.x;
    o.y = dy * rstd * g.y + b.y;
    o.z = dz * rstd * g.z + b.z;
    o.w = dw * rstd * g.w + b.w;
    *(float4*)(out + (size_t)row * DD + lane * 4) = o;
}

extern "C" void kernel_launch(void* const* d_in, const int* in_sizes, int n_in,
                              void* d_out, int out_size, void* d_ws, size_t ws_size,
                              hipStream_t stream) {
    const float* hidden = (const float*)d_in[0];
    const float* amask  = (const float*)d_in[1];
    const int*   src    = (const int*)d_in[2];
    const int*   dst    = (const int*)d_in[3];
    const float* Wqkv   = (const float*)d_in[4];
    const float* bqkv   = (const float*)d_in[5];
    const float* Wo     = (const float*)d_in[6];
    const float* bo     = (const float*)d_in[7];
    const float* gamma  = (const float*)d_in[8];
    const float* beta   = (const float*)d_in[9];
    float* out = (float*)d_out;

    char* p = (char*)d_ws;
    u16*      hidb   = (u16*)p;      p += (size_t)NN * DD * 2;     // 8 MB bf16 hidden
    u16*      WtQ    = (u16*)p;      p += (size_t)D3 * DD * 2;     // 384 KB
    u16*      WtO    = (u16*)p;      p += (size_t)DD * DD * 2;     // 128 KB
    float*    biasq  = (float*)p;    p += (size_t)D3 * 4;
    float*    biaso  = (float*)p;    p += (size_t)DD * 4;
    u16*      qb     = (u16*)p;      p += (size_t)NN * DD * 2;     // 8 MB
    u16*      kb     = (u16*)p;      p += (size_t)NN * DD * 2;     // 8 MB
    u16*      hA     = (u16*)p;      p += (size_t)NN * DD * 2;     // 8 MB
    u16*      hB     = (u16*)p;      p += (size_t)NN * DD * 2;     // 8 MB
    u16*      gbf    = (u16*)p;      p += (size_t)NN * DD * 2;     // 8 MB final gather bf16
    float*    gather = (float*)p;    p += (size_t)NN * DD * 4;     // 16 MB fp32 accumulator
    float*    attn   = (float*)p;    p += (size_t)EE * HH * 4;     // 8 MB
    float*    y      = (float*)p;    p += (size_t)NN * DD * 4;     // 16 MB
    float*    nmask  = (float*)p;    p += (size_t)NN * 4;
    int*      deg    = (int*)p;      p += (size_t)NN * 4;
    int*      offs   = (int*)p;      p += (size_t)(NN + 1) * 4;
    int*      cursor = (int*)p;      p += (size_t)NN * 4;
    int*      epos   = (int*)p;      p += (size_t)EE * 4;
    int*      srcs   = (int*)p;      p += (size_t)EE * 4;

    // 1. node mask + bf16 conversions
    node_mask_kernel<<<NN / 256, 256, 0, stream>>>(amask, nmask);
    hconv_kernel<<<(NN * DD / 4) / 256, 256, 0, stream>>>(hidden, (unsigned*)hidb);
    wconv_kernel<<<(D3 * DD) / 256, 256, 0, stream>>>(Wqkv, bqkv, WtQ, biasq, D3, DD);
    wconv_kernel<<<(DD * DD) / 256, 256, 0, stream>>>(Wo, bo, WtO, biaso, DD, 0);

    // 2. CSR build over dst
    hipMemsetAsync(deg, 0, (size_t)NN * 4, stream);
    hist_kernel<<<EE / 256, 256, 0, stream>>>(dst, deg);
    scan_kernel<<<1, 1024, 0, stream>>>(deg, offs, cursor, NN);
    scatter_kernel<<<EE / 256, 256, 0, stream>>>(dst, cursor, epos);

    // 3. QKV projection (MFMA) with fused q/k/v epilogue
    mfma_gemm_kernel<0><<<dim3(D3 / 128, NN / 128), 256, 0, stream>>>(
        hidb, WtQ, biasq, qb, kb, hA, gather, nullptr, nullptr);

    // 4. edge scores in CSR order
    edge_score_kernel<<<(EE * HH) / 256, 256, 0, stream>>>(
        (const unsigned*)qb, (const unsigned*)kb, src, dst, epos, nmask, attn, srcs);

    // 5. segment softmax
    softmax_kernel<<<(NN * HH) / 256, 256, 0, stream>>>(offs, attn);

    // 6. diffusion: gather = h0 + h1 + h2/2 + h3/6 (last pass emits bf16)
    diffuse_kernel<<<(NN * 128) / 256, 256, 0, stream>>>(
        offs, srcs, attn, (const unsigned*)hA, (unsigned*)hB, gather, nullptr, 1.0f);
    diffuse_kernel<<<(NN * 128) / 256, 256, 0, stream>>>(
        offs, srcs, attn, (const unsigned*)hB, (unsigned*)hA, gather, nullptr, 0.5f);
    diffuse_kernel<<<(NN * 128) / 256, 256, 0, stream>>>(
        offs, srcs, attn, (const unsigned*)hA, nullptr, gather, (unsigned*)gbf, 1.0f / 6.0f);

    // 7. output projection + residual (MFMA) -> y
    mfma_gemm_kernel<1><<<dim3(DD / 128, NN / 128), 256, 0, stream>>>(
        gbf, WtO, biaso, nullptr, nullptr, nullptr, nullptr, hidden, y);

    // 8. LayerNorm
    ln_kernel<<<NN / 4, 256, 0, stream>>>(y, gamma, beta, out);
}

// Round 4
// 281.515 us; speedup vs baseline: 2.7393x; 1.3710x over previous
//
#include <hip/hip_runtime.h>
#include <math.h>

#define NN 16384      // B*S nodes
#define DD 256        // model dim
#define HH 8          // heads
#define HDIM 32       // head dim
#define EE 262144     // edges
#define D3 768        // 3*D
#define QSCALE 0.17677669529663687f   // 1/sqrt(32)
#define EXPN1 0.36787944117144233f    // exp(-1)
#define LN_EPS 1e-12f

typedef short bf16x8 __attribute__((ext_vector_type(8)));
typedef float f32x4 __attribute__((ext_vector_type(4)));
typedef unsigned short u16;

// ---- bf16 helpers (bit tricks) ----
__device__ __forceinline__ float bf_lo(unsigned u) { return __uint_as_float(u << 16); }
__device__ __forceinline__ float bf_hi(unsigned u) { return __uint_as_float(u & 0xffff0000u); }
__device__ __forceinline__ unsigned f2bf(float f) {  // RNE, result in low 16
    unsigned b = __float_as_uint(f);
    return (b + 0x7fffu + ((b >> 16) & 1u)) >> 16;
}
__device__ __forceinline__ unsigned pack2bf(float lo, float hi) {
    return f2bf(lo) | (f2bf(hi) << 16);
}

// ---------------- node mask ----------------
__global__ void node_mask_kernel(const float* __restrict__ am, float* __restrict__ nmask) {
    int i = blockIdx.x * 256 + threadIdx.x;
    nmask[i] = (am[i] >= 0.0f) ? 1.0f : 0.0f;
}

// ---------------- hidden fp32 -> bf16 ----------------
__global__ void hconv_kernel(const float* __restrict__ x, unsigned* __restrict__ xb) {
    int gid = blockIdx.x * 256 + threadIdx.x;   // one per 4 floats
    float4 v = *(const float4*)(x + (size_t)gid * 4);
    uint2 o;
    o.x = pack2bf(v.x, v.y);
    o.y = pack2bf(v.z, v.w);
    *(uint2*)(xb + (size_t)gid * 2) = o;
}

// ---------------- weight transpose + bf16 (+ q-scale fold + scaled bias) ----------------
__global__ void wconv_kernel(const float* __restrict__ W, const float* __restrict__ b,
                             u16* __restrict__ Wt, float* __restrict__ bias_s,
                             int Nw, int scale_cols) {
    int gid = blockIdx.x * 256 + threadIdx.x;   // n*256 + k
    int n = gid >> 8, k = gid & 255;
    float s = (n < scale_cols) ? QSCALE : 1.0f;
    Wt[(size_t)n * 256 + k] = (u16)f2bf(W[(size_t)k * Nw + n] * s);
    if (k == 0) bias_s[n] = b[n] * s;
}

// ---------------- MFMA GEMM: C[M,Nc] = Abf[M,256] @ Bt[Nc,256]^T + bias ----------------
template <int MODE>
__global__ __launch_bounds__(256) void mfma_gemm_kernel(
        const u16* __restrict__ Ab, const u16* __restrict__ Bt,
        const float* __restrict__ bias,
        u16* __restrict__ qb, u16* __restrict__ kb,
        u16* __restrict__ hA, float* __restrict__ gather,
        const float* __restrict__ resid, float* __restrict__ y) {
    __shared__ u16 As[128 * 40];
    __shared__ u16 Bs[128 * 40];
    const int tid = threadIdx.x;
    const int m0 = blockIdx.y * 128;
    const int n0 = blockIdx.x * 128;
    const int wave = tid >> 6, lane = tid & 63;
    const int wr = wave >> 1, wc = wave & 1;
    const int lm = lane & 15, quad = lane >> 4;

    f32x4 acc[4][4] = {};

    const int r0 = tid >> 2;             // 0..63
    const int c8 = (tid & 3) * 8;        // 0,8,16,24

    for (int k0 = 0; k0 < 256; k0 += 32) {
        #pragma unroll
        for (int s = 0; s < 2; ++s) {
            int r = r0 + s * 64;
            *(uint4*)&As[r * 40 + c8] = *(const uint4*)(Ab + (size_t)(m0 + r) * 256 + k0 + c8);
            *(uint4*)&Bs[r * 40 + c8] = *(const uint4*)(Bt + (size_t)(n0 + r) * 256 + k0 + c8);
        }
        __syncthreads();
        bf16x8 af[4], bfv[4];
        #pragma unroll
        for (int mi = 0; mi < 4; ++mi)
            af[mi] = *(const bf16x8*)&As[(wr * 64 + mi * 16 + lm) * 40 + quad * 8];
        #pragma unroll
        for (int ni = 0; ni < 4; ++ni)
            bfv[ni] = *(const bf16x8*)&Bs[(wc * 64 + ni * 16 + lm) * 40 + quad * 8];
        #pragma unroll
        for (int mi = 0; mi < 4; ++mi)
            #pragma unroll
            for (int ni = 0; ni < 4; ++ni)
                acc[mi][ni] = __builtin_amdgcn_mfma_f32_16x16x32_bf16(
                    af[mi], bfv[ni], acc[mi][ni], 0, 0, 0);
        __syncthreads();
    }

    if (MODE == 0) {
        const int type = n0 >> 8;        // 0=q 1=k 2=v
        const int cb = n0 & 255;
        #pragma unroll
        for (int mi = 0; mi < 4; ++mi) {
            #pragma unroll
            for (int j = 0; j < 4; ++j) {
                int m = m0 + wr * 64 + mi * 16 + quad * 4 + j;
                #pragma unroll
                for (int ni = 0; ni < 4; ++ni) {
                    int nl = wc * 64 + ni * 16 + lm;
                    float val = acc[mi][ni][j] + bias[n0 + nl];
                    size_t off = (size_t)m * 256 + cb + nl;
                    if (type == 0) qb[off] = (u16)f2bf(val);
                    else if (type == 1) kb[off] = (u16)f2bf(val);
                    else {
                        float hx = val * EXPN1;
                        hA[off] = (u16)f2bf(hx);
                        gather[off] = hx;
                    }
                }
            }
        }
    } else {
        #pragma unroll
        for (int mi = 0; mi < 4; ++mi) {
            #pragma unroll
            for (int j = 0; j < 4; ++j) {
                int m = m0 + wr * 64 + mi * 16 + quad * 4 + j;
                #pragma unroll
                for (int ni = 0; ni < 4; ++ni) {
                    int nl = wc * 64 + ni * 16 + lm;
                    size_t off = (size_t)m * 256 + n0 + nl;
                    y[off] = acc[mi][ni][j] + bias[n0 + nl] + resid[off];
                }
            }
        }
    }
}

// ---------------- CSR build: histogram / scan / scatter ----------------
__global__ void hist_kernel(const int* __restrict__ dst, int* __restrict__ deg) {
    int e = blockIdx.x * 256 + threadIdx.x;
    atomicAdd(&deg[dst[e]], 1);
}

__global__ __launch_bounds__(1024) void scan_kernel(const int* __restrict__ deg,
                                                    int* __restrict__ offs,
                                                    int* __restrict__ cursor, int n) {
    __shared__ int part[1024];
    int t = threadIdx.x;
    int base = t * 16;
    int local[16];
    int s = 0;
    #pragma unroll
    for (int i = 0; i < 16; ++i) { local[i] = s; s += deg[base + i]; }
    part[t] = s;
    __syncthreads();
    for (int d = 1; d < 1024; d <<= 1) {
        int add = (t >= d) ? part[t - d] : 0;
        __syncthreads();
        part[t] += add;
        __syncthreads();
    }
    int excl = part[t] - s;
    #pragma unroll
    for (int i = 0; i < 16; ++i) {
        offs[base + i] = excl + local[i];
        cursor[base + i] = excl + local[i];
    }
    if (t == 1023) offs[n] = excl + s;
}

// scatter: write per-CSR-slot src and dst directly
__global__ void scatter_kernel(const int* __restrict__ src, const int* __restrict__ dst,
                               int* __restrict__ cursor,
                               int* __restrict__ srcs, int* __restrict__ dstc) {
    int e = blockIdx.x * 256 + threadIdx.x;
    int d = dst[e];
    int pos = atomicAdd(&cursor[d], 1);
    srcs[pos] = src[e];
    dstc[pos] = d;
}

// ---------------- per-(slot,head) scores, CSR-ordered (q reads are dst-local) ----------------
__global__ void edge_score_kernel(const unsigned* __restrict__ qb, const unsigned* __restrict__ kb,
                                  const int* __restrict__ srcs, const int* __restrict__ dstc,
                                  const float* __restrict__ nmask, float* __restrict__ attn) {
    int idx = blockIdx.x * 256 + threadIdx.x;   // pos*8 + h
    int p = idx >> 3, h = idx & 7;
    int s = srcs[p], d = dstc[p];
    const uint4* kp = (const uint4*)(kb + (size_t)s * 128 + h * 16);
    const uint4* qp = (const uint4*)(qb + (size_t)d * 128 + h * 16);
    float acc = 0.0f;
    #pragma unroll
    for (int i = 0; i < 4; ++i) {
        uint4 kv = kp[i], qv = qp[i];
        acc += bf_lo(kv.x) * bf_lo(qv.x) + bf_hi(kv.x) * bf_hi(qv.x);
        acc += bf_lo(kv.y) * bf_lo(qv.y) + bf_hi(kv.y) * bf_hi(qv.y);
        acc += bf_lo(kv.z) * bf_lo(qv.z) + bf_hi(kv.z) * bf_hi(qv.z);
        acc += bf_lo(kv.w) * bf_lo(qv.w) + bf_hi(kv.w) * bf_hi(qv.w);
    }
    bool valid = (nmask[s] != 0.0f) && (nmask[d] != 0.0f);
    attn[(size_t)p * 8 + h] = valid ? acc : -10000.0f;
}

// ---------------- per-(node,head) segment softmax ----------------
__global__ void softmax_kernel(const int* __restrict__ offs, float* __restrict__ attn) {
    int gid = blockIdx.x * 256 + threadIdx.x;   // node*8 + h
    int node = gid >> 3, h = gid & 7;
    int beg = offs[node], end = offs[node + 1];
    if (beg == end) return;
    float m = -INFINITY;
    for (int i = beg; i < end; ++i) m = fmaxf(m, attn[(size_t)i * 8 + h]);
    float den = 0.0f;
    for (int i = beg; i < end; ++i) {
        float es = __expf(attn[(size_t)i * 8 + h] - m);
        attn[(size_t)i * 8 + h] = es;
        den += es;
    }
    float inv = 1.0f / den;
    for (int i = beg; i < end; ++i) attn[(size_t)i * 8 + h] *= inv;
}

// ---------------- diffusion step: one wave per node, 4 channels/thread, 8-edge batches ----
__global__ void diffuse_kernel(const int* __restrict__ offs, const int* __restrict__ srcs,
                               const float* __restrict__ attn,
                               const uint2* __restrict__ hcur, uint2* __restrict__ hnext,
                               float* __restrict__ gather, uint2* __restrict__ gout,
                               float fact) {
    int gid = blockIdx.x * 256 + threadIdx.x;
    int node = gid >> 6;
    int j2 = gid & 63;          // channels 4*j2 .. 4*j2+3
    int h = j2 >> 3;
    int beg = offs[node], end = offs[node + 1];
    float a0 = 0.0f, a1 = 0.0f, a2 = 0.0f, a3 = 0.0f;
    int i = beg;
    // full batches of 8: 8 independent meta loads, then 8 independent gathers
    for (; i + 8 <= end; i += 8) {
        int sarr[8]; float aarr[8]; uint2 hv[8];
        #pragma unroll
        for (int t = 0; t < 8; ++t) {
            sarr[t] = srcs[i + t];
            aarr[t] = attn[(size_t)(i + t) * 8 + h];
        }
        #pragma unroll
        for (int t = 0; t < 8; ++t) hv[t] = hcur[(size_t)sarr[t] * 64 + j2];
        #pragma unroll
        for (int t = 0; t < 8; ++t) {
            float a = aarr[t];
            a0 += a * bf_lo(hv[t].x); a1 += a * bf_hi(hv[t].x);
            a2 += a * bf_lo(hv[t].y); a3 += a * bf_hi(hv[t].y);
        }
    }
    // remainder (wave-uniform predication)
    if (i < end) {
        int cnt = end - i;
        int sarr[8]; float aarr[8]; uint2 hv[8];
        #pragma unroll
        for (int t = 0; t < 8; ++t) if (t < cnt) {
            sarr[t] = srcs[i + t];
            aarr[t] = attn[(size_t)(i + t) * 8 + h];
        }
        #pragma unroll
        for (int t = 0; t < 8; ++t) if (t < cnt) hv[t] = hcur[(size_t)sarr[t] * 64 + j2];
        #pragma unroll
        for (int t = 0; t < 8; ++t) if (t < cnt) {
            float a = aarr[t];
            a0 += a * bf_lo(hv[t].x); a1 += a * bf_hi(hv[t].x);
            a2 += a * bf_lo(hv[t].y); a3 += a * bf_hi(hv[t].y);
        }
    }
    if (hnext) hnext[(size_t)node * 64 + j2] = make_uint2(pack2bf(a0, a1), pack2bf(a2, a3));
    float4* gp = (float4*)(gather + (size_t)node * DD + 4 * j2);
    float4 g = *gp;
    g.x += fact * a0; g.y += fact * a1; g.z += fact * a2; g.w += fact * a3;
    if (gout) gout[(size_t)node * 64 + j2] = make_uint2(pack2bf(g.x, g.y), pack2bf(g.z, g.w));
    else *gp = g;
}

// ---------------- LayerNorm, one wave per row ----------------
__global__ __launch_bounds__(256) void ln_kernel(const float* __restrict__ y,
                                                 const float* __restrict__ gamma,
                                                 const float* __restrict__ beta,
                                                 float* __restrict__ out) {
    int wave = threadIdx.x >> 6;
    int lane = threadIdx.x & 63;
    int row = blockIdx.x * 4 + wave;
    const float* yr = y + (size_t)row * DD;
    float4 v = *(const float4*)(yr + lane * 4);
    float s = v.x + v.y + v.z + v.w;
    #pragma unroll
    for (int m = 32; m >= 1; m >>= 1) s += __shfl_xor(s, m);
    float mu = s * (1.0f / 256.0f);
    float dx = v.x - mu, dy = v.y - mu, dz = v.z - mu, dw = v.w - mu;
    float sq = dx * dx + dy * dy + dz * dz + dw * dw;
    #pragma unroll
    for (int m = 32; m >= 1; m >>= 1) sq += __shfl_xor(sq, m);
    float var = sq * (1.0f / 256.0f);
    float rstd = 1.0f / sqrtf(var + LN_EPS);
    float4 g = *(const float4*)(gamma + lane * 4);
    float4 b = *(const float4*)(beta + lane * 4);
    float4 o;
    o.x = dx * rstd * g.x + b.x;
    o.y = dy * rstd * g.y + b.y;
    o.z = dz * rstd * g.z + b.z;
    o.w = dw * rstd * g.w + b.w;
    *(float4*)(out + (size_t)row * DD + lane * 4) = o;
}

extern "C" void kernel_launch(void* const* d_in, const int* in_sizes, int n_in,
                              void* d_out, int out_size, void* d_ws, size_t ws_size,
                              hipStream_t stream) {
    const float* hidden = (const float*)d_in[0];
    const float* amask  = (const float*)d_in[1];
    const int*   src    = (const int*)d_in[2];
    const int*   dst    = (const int*)d_in[3];
    const float* Wqkv   = (const float*)d_in[4];
    const float* bqkv   = (const float*)d_in[5];
    const float* Wo     = (const float*)d_in[6];
    const float* bo     = (const float*)d_in[7];
    const float* gamma  = (const float*)d_in[8];
    const float* beta   = (const float*)d_in[9];
    float* out = (float*)d_out;

    char* p = (char*)d_ws;
    u16*      hidb   = (u16*)p;      p += (size_t)NN * DD * 2;     // 8 MB
    u16*      WtQ    = (u16*)p;      p += (size_t)D3 * DD * 2;
    u16*      WtO    = (u16*)p;      p += (size_t)DD * DD * 2;
    float*    biasq  = (float*)p;    p += (size_t)D3 * 4;
    float*    biaso  = (float*)p;    p += (size_t)DD * 4;
    u16*      qb     = (u16*)p;      p += (size_t)NN * DD * 2;     // 8 MB
    u16*      kb     = (u16*)p;      p += (size_t)NN * DD * 2;     // 8 MB
    u16*      hA     = (u16*)p;      p += (size_t)NN * DD * 2;     // 8 MB
    u16*      hB     = (u16*)p;      p += (size_t)NN * DD * 2;     // 8 MB
    u16*      gbf    = (u16*)p;      p += (size_t)NN * DD * 2;     // 8 MB
    float*    gather = (float*)p;    p += (size_t)NN * DD * 4;     // 16 MB
    float*    attn   = (float*)p;    p += (size_t)EE * HH * 4;     // 8 MB
    float*    y      = (float*)p;    p += (size_t)NN * DD * 4;     // 16 MB
    float*    nmask  = (float*)p;    p += (size_t)NN * 4;
    int*      deg    = (int*)p;      p += (size_t)NN * 4;
    int*      offs   = (int*)p;      p += (size_t)(NN + 1) * 4;
    int*      cursor = (int*)p;      p += (size_t)NN * 4;
    int*      srcs   = (int*)p;      p += (size_t)EE * 4;
    int*      dstc   = (int*)p;      p += (size_t)EE * 4;

    // 1. node mask + bf16 conversions
    node_mask_kernel<<<NN / 256, 256, 0, stream>>>(amask, nmask);
    hconv_kernel<<<(NN * DD / 4) / 256, 256, 0, stream>>>(hidden, (unsigned*)hidb);
    wconv_kernel<<<(D3 * DD) / 256, 256, 0, stream>>>(Wqkv, bqkv, WtQ, biasq, D3, DD);
    wconv_kernel<<<(DD * DD) / 256, 256, 0, stream>>>(Wo, bo, WtO, biaso, DD, 0);

    // 2. CSR build over dst
    hipMemsetAsync(deg, 0, (size_t)NN * 4, stream);
    hist_kernel<<<EE / 256, 256, 0, stream>>>(dst, deg);
    scan_kernel<<<1, 1024, 0, stream>>>(deg, offs, cursor, NN);
    scatter_kernel<<<EE / 256, 256, 0, stream>>>(src, dst, cursor, srcs, dstc);

    // 3. QKV projection (MFMA) with fused q/k/v epilogue
    mfma_gemm_kernel<0><<<dim3(D3 / 128, NN / 128), 256, 0, stream>>>(
        hidb, WtQ, biasq, qb, kb, hA, gather, nullptr, nullptr);

    // 4. edge scores in CSR order (dst-local q reads)
    edge_score_kernel<<<(EE * HH) / 256, 256, 0, stream>>>(
        (const unsigned*)qb, (const unsigned*)kb, srcs, dstc, nmask, attn);

    // 5. segment softmax
    softmax_kernel<<<(NN * HH) / 256, 256, 0, stream>>>(offs, attn);

    // 6. diffusion: gather = h0 + h1 + h2/2 + h3/6 (last pass emits bf16)
    diffuse_kernel<<<(NN * 64) / 256, 256, 0, stream>>>(
        offs, srcs, attn, (const uint2*)hA, (uint2*)hB, gather, nullptr, 1.0f);
    diffuse_kernel<<<(NN * 64) / 256, 256, 0, stream>>>(
        offs, srcs, attn, (const uint2*)hB, (uint2*)hA, gather, nullptr, 0.5f);
    diffuse_kernel<<<(NN * 64) / 256, 256, 0, stream>>>(
        offs, srcs, attn, (const uint2*)hA, nullptr, gather, (uint2*)gbf, 1.0f / 6.0f);

    // 7. output projection + residual (MFMA) -> y
    mfma_gemm_kernel<1><<<dim3(DD / 128, NN / 128), 256, 0, stream>>>(
        gbf, WtO, biaso, nullptr, nullptr, nullptr, nullptr, hidden, y);

    // 8. LayerNorm
    ln_kernel<<<NN / 4, 256, 0, stream>>>(y, gamma, beta, out);
}

// Round 5
// 240.155 us; speedup vs baseline: 3.2111x; 1.1722x over previous
//
#include <hip/hip_runtime.h>
#include <math.h>

#define NN 16384      // B*S nodes
#define DD 256        // model dim
#define HH 8          // heads
#define EE 262144     // edges
#define D3 768        // 3*D
#define QSCALE 0.17677669529663687f   // 1/sqrt(32)
#define EXPN1 0.36787944117144233f    // exp(-1)
#define LN_EPS 1e-12f

typedef short bf16x8 __attribute__((ext_vector_type(8)));
typedef float f32x4 __attribute__((ext_vector_type(4)));
typedef float f32x2 __attribute__((ext_vector_type(2)));
typedef unsigned short u16;
typedef unsigned char u8;

// ---- bf16 helpers ----
__device__ __forceinline__ float bf_lo(unsigned u) { return __uint_as_float(u << 16); }
__device__ __forceinline__ float bf_hi(unsigned u) { return __uint_as_float(u & 0xffff0000u); }
__device__ __forceinline__ unsigned f2bf(float f) {  // RNE
    unsigned b = __float_as_uint(f);
    return (b + 0x7fffu + ((b >> 16) & 1u)) >> 16;
}
__device__ __forceinline__ unsigned pack2bf(float lo, float hi) {
    return f2bf(lo) | (f2bf(hi) << 16);
}
// ---- fp8 e4m3 helpers (HW cvt) ----
__device__ __forceinline__ u8 f2fp8(float v) {
    return (u8)(__builtin_amdgcn_cvt_pk_fp8_f32(v, v, 0, false) & 0xff);
}

// ---------------- hidden fp32 -> bf16 ----------------
__global__ void hconv_kernel(const float* __restrict__ x, unsigned* __restrict__ xb) {
    int gid = blockIdx.x * 256 + threadIdx.x;   // one per 4 floats
    float4 v = *(const float4*)(x + (size_t)gid * 4);
    uint2 o;
    o.x = pack2bf(v.x, v.y);
    o.y = pack2bf(v.z, v.w);
    *(uint2*)(xb + (size_t)gid * 2) = o;
}

// ---------------- weight transpose + bf16 (+ q-scale fold) ----------------
__global__ void wconv_kernel(const float* __restrict__ W, const float* __restrict__ b,
                             u16* __restrict__ Wt, float* __restrict__ bias_s,
                             int Nw, int scale_cols) {
    int gid = blockIdx.x * 256 + threadIdx.x;   // n*256 + k
    int n = gid >> 8, k = gid & 255;
    float s = (n < scale_cols) ? QSCALE : 1.0f;
    Wt[(size_t)n * 256 + k] = (u16)f2bf(W[(size_t)k * Nw + n] * s);
    if (k == 0) bias_s[n] = b[n] * s;
}

// ---------------- MFMA GEMM1: qkv = hid @ WtQ^T + bias; epilogue -> qb(bf16)/kb8(fp8)/h8+gather ----
__global__ __launch_bounds__(256) void mfma_gemm1_kernel(
        const u16* __restrict__ Ab, const u16* __restrict__ Bt,
        const float* __restrict__ bias,
        u16* __restrict__ qb, u8* __restrict__ kb8,
        u8* __restrict__ h8, float* __restrict__ gather) {
    __shared__ u16 As[128 * 40];
    __shared__ u16 Bs[128 * 40];
    const int tid = threadIdx.x;
    const int m0 = blockIdx.y * 128;
    const int n0 = blockIdx.x * 128;
    const int wave = tid >> 6, lane = tid & 63;
    const int wr = wave >> 1, wc = wave & 1;
    const int lm = lane & 15, quad = lane >> 4;

    f32x4 acc[4][4] = {};
    const int r0 = tid >> 2;
    const int c8 = (tid & 3) * 8;

    for (int k0 = 0; k0 < 256; k0 += 32) {
        #pragma unroll
        for (int s = 0; s < 2; ++s) {
            int r = r0 + s * 64;
            *(uint4*)&As[r * 40 + c8] = *(const uint4*)(Ab + (size_t)(m0 + r) * 256 + k0 + c8);
            *(uint4*)&Bs[r * 40 + c8] = *(const uint4*)(Bt + (size_t)(n0 + r) * 256 + k0 + c8);
        }
        __syncthreads();
        bf16x8 af[4], bfv[4];
        #pragma unroll
        for (int mi = 0; mi < 4; ++mi)
            af[mi] = *(const bf16x8*)&As[(wr * 64 + mi * 16 + lm) * 40 + quad * 8];
        #pragma unroll
        for (int ni = 0; ni < 4; ++ni)
            bfv[ni] = *(const bf16x8*)&Bs[(wc * 64 + ni * 16 + lm) * 40 + quad * 8];
        #pragma unroll
        for (int mi = 0; mi < 4; ++mi)
            #pragma unroll
            for (int ni = 0; ni < 4; ++ni)
                acc[mi][ni] = __builtin_amdgcn_mfma_f32_16x16x32_bf16(
                    af[mi], bfv[ni], acc[mi][ni], 0, 0, 0);
        __syncthreads();
    }

    const int type = n0 >> 8;        // 0=q 1=k 2=v
    const int cb = n0 & 255;
    #pragma unroll
    for (int mi = 0; mi < 4; ++mi) {
        #pragma unroll
        for (int j = 0; j < 4; ++j) {
            int m = m0 + wr * 64 + mi * 16 + quad * 4 + j;
            #pragma unroll
            for (int ni = 0; ni < 4; ++ni) {
                int nl = wc * 64 + ni * 16 + lm;
                float val = acc[mi][ni][j] + bias[n0 + nl];
                size_t off = (size_t)m * 256 + cb + nl;
                if (type == 0) qb[off] = (u16)f2bf(val);
                else if (type == 1) kb8[off] = f2fp8(val);
                else {
                    float hx = val * EXPN1;
                    h8[off] = f2fp8(hx);
                    gather[off] = hx;
                }
            }
        }
    }
}

// ---------------- CSR build: histogram / scan / scatter ----------------
__global__ void hist_kernel(const int* __restrict__ dst, int* __restrict__ deg) {
    int e = blockIdx.x * 256 + threadIdx.x;
    atomicAdd(&deg[dst[e]], 1);
}

__global__ __launch_bounds__(1024) void scan_kernel(const int* __restrict__ deg,
                                                    int* __restrict__ offs,
                                                    int* __restrict__ cursor, int n) {
    __shared__ int part[1024];
    int t = threadIdx.x;
    int base = t * 16;
    int local[16];
    int s = 0;
    #pragma unroll
    for (int i = 0; i < 16; ++i) { local[i] = s; s += deg[base + i]; }
    part[t] = s;
    __syncthreads();
    for (int d = 1; d < 1024; d <<= 1) {
        int add = (t >= d) ? part[t - d] : 0;
        __syncthreads();
        part[t] += add;
        __syncthreads();
    }
    int excl = part[t] - s;
    #pragma unroll
    for (int i = 0; i < 16; ++i) {
        offs[base + i] = excl + local[i];
        cursor[base + i] = excl + local[i];
    }
    if (t == 1023) offs[n] = excl + s;
}

__global__ void scatter_kernel(const int* __restrict__ src, const int* __restrict__ dst,
                               int* __restrict__ cursor,
                               int* __restrict__ srcs, int* __restrict__ dstc) {
    int e = blockIdx.x * 256 + threadIdx.x;
    int d = dst[e];
    int pos = atomicAdd(&cursor[d], 1);
    srcs[pos] = src[e];
    dstc[pos] = d;
}

// ---------------- per-(slot,head) scores: k fp8 gather, q bf16 (dst-local) ----------------
__global__ void edge_score_kernel(const unsigned* __restrict__ qb, const u8* __restrict__ kb8,
                                  const int* __restrict__ srcs, const int* __restrict__ dstc,
                                  const float* __restrict__ amask, float* __restrict__ attn) {
    int idx = blockIdx.x * 256 + threadIdx.x;   // pos*8 + h
    int p = idx >> 3, h = idx & 7;
    int s = srcs[p], d = dstc[p];
    const uint4* kp = (const uint4*)(kb8 + (size_t)s * 256 + h * 32);
    const uint4* qp = (const uint4*)(qb + (size_t)d * 128 + h * 16);
    uint4 k0 = kp[0], k1 = kp[1];
    unsigned kk[8] = {k0.x, k0.y, k0.z, k0.w, k1.x, k1.y, k1.z, k1.w};
    uint4 q0 = qp[0], q1 = qp[1], q2 = qp[2], q3 = qp[3];
    unsigned qq[16] = {q0.x, q0.y, q0.z, q0.w, q1.x, q1.y, q1.z, q1.w,
                       q2.x, q2.y, q2.z, q2.w, q3.x, q3.y, q3.z, q3.w};
    float acc = 0.0f;
    #pragma unroll
    for (int t = 0; t < 8; ++t) {
        f32x2 a = __builtin_amdgcn_cvt_pk_f32_fp8(kk[t], false);
        f32x2 b = __builtin_amdgcn_cvt_pk_f32_fp8(kk[t], true);
        acc += a.x * bf_lo(qq[2 * t]) + a.y * bf_hi(qq[2 * t]);
        acc += b.x * bf_lo(qq[2 * t + 1]) + b.y * bf_hi(qq[2 * t + 1]);
    }
    bool valid = (amask[s] >= 0.0f) && (amask[d] >= 0.0f);
    attn[(size_t)p * 8 + h] = valid ? acc : -10000.0f;
}

// ---------------- segment softmax: write unnormalized exp + inv(1/den) ----------------
__global__ void softmax_kernel(const int* __restrict__ offs, float* __restrict__ attn,
                               float* __restrict__ inv) {
    int gid = blockIdx.x * 256 + threadIdx.x;   // node*8 + h
    int node = gid >> 3, h = gid & 7;
    int beg = offs[node], end = offs[node + 1];
    if (beg == end) { inv[gid] = 0.0f; return; }
    float m = -INFINITY;
    for (int i = beg; i < end; ++i) m = fmaxf(m, attn[(size_t)i * 8 + h]);
    float den = 0.0f;
    for (int i = beg; i < end; ++i) {
        float es = __expf(attn[(size_t)i * 8 + h] - m);
        attn[(size_t)i * 8 + h] = es;
        den += es;
    }
    inv[gid] = 1.0f / den;
}

// ---------------- diffusion: one wave/node, 4 ch/thread, fp8 h gathers, 8-edge batches ----
__global__ void diffuse_kernel(const int* __restrict__ offs, const int* __restrict__ srcs,
                               const float* __restrict__ attn, const float* __restrict__ inv,
                               const unsigned* __restrict__ hcur, unsigned* __restrict__ hnext,
                               float* __restrict__ gather, uint2* __restrict__ gout,
                               float fact) {
    int gid = blockIdx.x * 256 + threadIdx.x;
    int node = gid >> 6;
    int j2 = gid & 63;          // channels 4*j2 .. 4*j2+3
    int h = j2 >> 3;
    int beg = offs[node], end = offs[node + 1];
    float a0 = 0.0f, a1 = 0.0f, a2 = 0.0f, a3 = 0.0f;
    int i = beg;
    for (; i + 8 <= end; i += 8) {
        int sarr[8]; float aarr[8]; unsigned hv[8];
        #pragma unroll
        for (int t = 0; t < 8; ++t) {
            sarr[t] = srcs[i + t];
            aarr[t] = attn[(size_t)(i + t) * 8 + h];
        }
        #pragma unroll
        for (int t = 0; t < 8; ++t) hv[t] = hcur[(size_t)sarr[t] * 64 + j2];
        #pragma unroll
        for (int t = 0; t < 8; ++t) {
            float a = aarr[t];
            f32x2 lo = __builtin_amdgcn_cvt_pk_f32_fp8(hv[t], false);
            f32x2 hi = __builtin_amdgcn_cvt_pk_f32_fp8(hv[t], true);
            a0 += a * lo.x; a1 += a * lo.y;
            a2 += a * hi.x; a3 += a * hi.y;
        }
    }
    if (i < end) {
        int cnt = end - i;
        int sarr[8]; float aarr[8]; unsigned hv[8];
        #pragma unroll
        for (int t = 0; t < 8; ++t) if (t < cnt) {
            sarr[t] = srcs[i + t];
            aarr[t] = attn[(size_t)(i + t) * 8 + h];
        }
        #pragma unroll
        for (int t = 0; t < 8; ++t) if (t < cnt) hv[t] = hcur[(size_t)sarr[t] * 64 + j2];
        #pragma unroll
        for (int t = 0; t < 8; ++t) if (t < cnt) {
            float a = aarr[t];
            f32x2 lo = __builtin_amdgcn_cvt_pk_f32_fp8(hv[t], false);
            f32x2 hi = __builtin_amdgcn_cvt_pk_f32_fp8(hv[t], true);
            a0 += a * lo.x; a1 += a * lo.y;
            a2 += a * hi.x; a3 += a * hi.y;
        }
    }
    float iv = inv[node * 8 + h];
    a0 *= iv; a1 *= iv; a2 *= iv; a3 *= iv;
    if (hnext) {
        int pk = __builtin_amdgcn_cvt_pk_fp8_f32(a0, a1, 0, false);
        pk = __builtin_amdgcn_cvt_pk_fp8_f32(a2, a3, pk, true);
        hnext[(size_t)node * 64 + j2] = (unsigned)pk;
    }
    float4* gp = (float4*)(gather + (size_t)node * DD + 4 * j2);
    float4 g = *gp;
    g.x += fact * a0; g.y += fact * a1; g.z += fact * a2; g.w += fact * a3;
    if (gout) gout[(size_t)node * 64 + j2] = make_uint2(pack2bf(g.x, g.y), pack2bf(g.z, g.w));
    else *gp = g;
}

// ---------------- GEMM2 (64x256 tile) + residual + fused LayerNorm ----------------
__global__ __launch_bounds__(256) void gemm2_ln_kernel(
        const u16* __restrict__ Ab, const u16* __restrict__ Bt,
        const float* __restrict__ bias, const float* __restrict__ resid,
        const float* __restrict__ gamma, const float* __restrict__ beta,
        float* __restrict__ out) {
    __shared__ u16 As[64 * 40];
    __shared__ u16 Bs[256 * 40];
    const int tid = threadIdx.x;
    const int m0 = blockIdx.x * 64;
    const int wave = tid >> 6, lane = tid & 63;
    const int lm = lane & 15, quad = lane >> 4;

    f32x4 acc[16] = {};
    for (int k0 = 0; k0 < 256; k0 += 32) {
        *(uint4*)&As[(tid >> 2) * 40 + (tid & 3) * 8] =
            *(const uint4*)(Ab + (size_t)(m0 + (tid >> 2)) * 256 + k0 + (tid & 3) * 8);
        {
            const uint4* srcp = (const uint4*)(Bt + (size_t)tid * 256 + k0);
            uint4* dstp = (uint4*)&Bs[tid * 40];
            dstp[0] = srcp[0]; dstp[1] = srcp[1]; dstp[2] = srcp[2]; dstp[3] = srcp[3];
        }
        __syncthreads();
        bf16x8 af = *(const bf16x8*)&As[(wave * 16 + lm) * 40 + quad * 8];
        #pragma unroll
        for (int ni = 0; ni < 16; ++ni) {
            bf16x8 bfv = *(const bf16x8*)&Bs[(ni * 16 + lm) * 40 + quad * 8];
            acc[ni] = __builtin_amdgcn_mfma_f32_16x16x32_bf16(af, bfv, acc[ni], 0, 0, 0);
        }
        __syncthreads();
    }

    // rows handled by this lane: m = m0 + wave*16 + quad*4 + j, j=0..3
    const int mrow = m0 + wave * 16 + quad * 4;
    float ga[16], be[16];
    float rowsum[4] = {}, rowsq[4] = {};
    #pragma unroll
    for (int ni = 0; ni < 16; ++ni) {
        int col = ni * 16 + lm;
        float bia = bias[col];
        ga[ni] = gamma[col]; be[ni] = beta[col];
        #pragma unroll
        for (int j = 0; j < 4; ++j) {
            float val = acc[ni][j] + bia + resid[(size_t)(mrow + j) * 256 + col];
            acc[ni][j] = val;
            rowsum[j] += val;
            rowsq[j] += val * val;
        }
    }
    #pragma unroll
    for (int j = 0; j < 4; ++j) {
        #pragma unroll
        for (int msk = 1; msk <= 8; msk <<= 1) {
            rowsum[j] += __shfl_xor(rowsum[j], msk);
            rowsq[j] += __shfl_xor(rowsq[j], msk);
        }
    }
    float mu[4], rstd[4];
    #pragma unroll
    for (int j = 0; j < 4; ++j) {
        mu[j] = rowsum[j] * (1.0f / 256.0f);
        float var = rowsq[j] * (1.0f / 256.0f) - mu[j] * mu[j];
        rstd[j] = 1.0f / sqrtf(var + LN_EPS);
    }
    #pragma unroll
    for (int ni = 0; ni < 16; ++ni) {
        int col = ni * 16 + lm;
        #pragma unroll
        for (int j = 0; j < 4; ++j)
            out[(size_t)(mrow + j) * 256 + col] = (acc[ni][j] - mu[j]) * rstd[j] * ga[ni] + be[ni];
    }
}

extern "C" void kernel_launch(void* const* d_in, const int* in_sizes, int n_in,
                              void* d_out, int out_size, void* d_ws, size_t ws_size,
                              hipStream_t stream) {
    const float* hidden = (const float*)d_in[0];
    const float* amask  = (const float*)d_in[1];
    const int*   src    = (const int*)d_in[2];
    const int*   dst    = (const int*)d_in[3];
    const float* Wqkv   = (const float*)d_in[4];
    const float* bqkv   = (const float*)d_in[5];
    const float* Wo     = (const float*)d_in[6];
    const float* bo     = (const float*)d_in[7];
    const float* gamma  = (const float*)d_in[8];
    const float* beta   = (const float*)d_in[9];
    float* out = (float*)d_out;

    char* p = (char*)d_ws;
    u16*      hidb   = (u16*)p;      p += (size_t)NN * DD * 2;     // 8 MB
    u16*      WtQ    = (u16*)p;      p += (size_t)D3 * DD * 2;
    u16*      WtO    = (u16*)p;      p += (size_t)DD * DD * 2;
    float*    biasq  = (float*)p;    p += (size_t)D3 * 4;
    float*    biaso  = (float*)p;    p += (size_t)DD * 4;
    u16*      qb     = (u16*)p;      p += (size_t)NN * DD * 2;     // 8 MB bf16
    u8*       kb8    = (u8*)p;       p += (size_t)NN * DD;         // 4 MB fp8
    u8*       h8A    = (u8*)p;       p += (size_t)NN * DD;         // 4 MB fp8
    u8*       h8B    = (u8*)p;       p += (size_t)NN * DD;         // 4 MB fp8
    u16*      gbf    = (u16*)p;      p += (size_t)NN * DD * 2;     // 8 MB bf16
    float*    gather = (float*)p;    p += (size_t)NN * DD * 4;     // 16 MB
    float*    attn   = (float*)p;    p += (size_t)EE * HH * 4;     // 8 MB
    float*    inv    = (float*)p;    p += (size_t)NN * HH * 4;     // 0.5 MB
    int*      deg    = (int*)p;      p += (size_t)NN * 4;
    int*      offs   = (int*)p;      p += (size_t)(NN + 1) * 4;
    int*      cursor = (int*)p;      p += (size_t)NN * 4;
    int*      srcs   = (int*)p;      p += (size_t)EE * 4;
    int*      dstc   = (int*)p;      p += (size_t)EE * 4;

    // 1. bf16 conversions
    hconv_kernel<<<(NN * DD / 4) / 256, 256, 0, stream>>>(hidden, (unsigned*)hidb);
    wconv_kernel<<<(D3 * DD) / 256, 256, 0, stream>>>(Wqkv, bqkv, WtQ, biasq, D3, DD);
    wconv_kernel<<<(DD * DD) / 256, 256, 0, stream>>>(Wo, bo, WtO, biaso, DD, 0);

    // 2. CSR build over dst
    hipMemsetAsync(deg, 0, (size_t)NN * 4, stream);
    hist_kernel<<<EE / 256, 256, 0, stream>>>(dst, deg);
    scan_kernel<<<1, 1024, 0, stream>>>(deg, offs, cursor, NN);
    scatter_kernel<<<EE / 256, 256, 0, stream>>>(src, dst, cursor, srcs, dstc);

    // 3. QKV projection (MFMA), fused epilogue -> qb bf16, kb8/h8 fp8, gather fp32
    mfma_gemm1_kernel<<<dim3(D3 / 128, NN / 128), 256, 0, stream>>>(
        hidb, WtQ, biasq, qb, kb8, h8A, gather);

    // 4. edge scores in CSR order
    edge_score_kernel<<<(EE * HH) / 256, 256, 0, stream>>>(
        (const unsigned*)qb, kb8, srcs, dstc, amask, attn);

    // 5. segment softmax -> unnormalized exp + inv
    softmax_kernel<<<(NN * HH) / 256, 256, 0, stream>>>(offs, attn, inv);

    // 6. diffusion: gather = h0 + h1 + h2/2 + h3/6 (fp8 h, inv folded, last pass emits bf16)
    diffuse_kernel<<<(NN * 64) / 256, 256, 0, stream>>>(
        offs, srcs, attn, inv, (const unsigned*)h8A, (unsigned*)h8B, gather, nullptr, 1.0f);
    diffuse_kernel<<<(NN * 64) / 256, 256, 0, stream>>>(
        offs, srcs, attn, inv, (const unsigned*)h8B, (unsigned*)h8A, gather, nullptr, 0.5f);
    diffuse_kernel<<<(NN * 64) / 256, 256, 0, stream>>>(
        offs, srcs, attn, inv, (const unsigned*)h8A, nullptr, gather, (uint2*)gbf, 1.0f / 6.0f);

    // 7. output projection + residual + fused LayerNorm -> out
    gemm2_ln_kernel<<<NN / 64, 256, 0, stream>>>(
        gbf, WtO, biaso, hidden, gamma, beta, out);
}

// Round 6
// 225.156 us; speedup vs baseline: 3.4250x; 1.0666x over previous
//
#include <hip/hip_runtime.h>
#include <math.h>

#define NN 16384      // B*S nodes
#define DD 256        // model dim
#define HH 8          // heads
#define EE 262144     // edges
#define D3 768        // 3*D
#define QSCALE 0.17677669529663687f   // 1/sqrt(32)
#define EXPN1 0.36787944117144233f    // exp(-1)
#define LN_EPS 1e-12f

typedef short bf16x8 __attribute__((ext_vector_type(8)));
typedef float f32x4 __attribute__((ext_vector_type(4)));
typedef float f32x2 __attribute__((ext_vector_type(2)));
typedef unsigned short u16;
typedef unsigned char u8;

// ---- bf16 helpers ----
__device__ __forceinline__ float bf_lo(unsigned u) { return __uint_as_float(u << 16); }
__device__ __forceinline__ float bf_hi(unsigned u) { return __uint_as_float(u & 0xffff0000u); }
__device__ __forceinline__ unsigned f2bf(float f) {  // RNE
    unsigned b = __float_as_uint(f);
    return (b + 0x7fffu + ((b >> 16) & 1u)) >> 16;
}
__device__ __forceinline__ unsigned pack2bf(float lo, float hi) {
    return f2bf(lo) | (f2bf(hi) << 16);
}
// ---- fp8 e4m3 helpers (HW cvt) ----
__device__ __forceinline__ u8 f2fp8(float v) {
    return (u8)(__builtin_amdgcn_cvt_pk_fp8_f32(v, v, 0, false) & 0xff);
}

// ---------------- prep: hconv (4096 blk) + wconvQ (768) + wconvO (256) + hist (1024) ----
__global__ void prep_kernel(const float* __restrict__ hidden, unsigned* __restrict__ hidb,
                            const float* __restrict__ Wqkv, const float* __restrict__ bqkv,
                            u16* __restrict__ WtQ, float* __restrict__ biasq,
                            const float* __restrict__ Wo, const float* __restrict__ bo,
                            u16* __restrict__ WtO, float* __restrict__ biaso,
                            const int* __restrict__ dst, int* __restrict__ deg) {
    int b = blockIdx.x;
    if (b < 4096) {                      // hidden fp32 -> bf16 (4 floats/thread)
        int gid = b * 256 + threadIdx.x;
        float4 v = *(const float4*)(hidden + (size_t)gid * 4);
        *(uint2*)(hidb + (size_t)gid * 2) = make_uint2(pack2bf(v.x, v.y), pack2bf(v.z, v.w));
    } else if (b < 4864) {               // Wqkv transpose+bf16, q-scale fold
        int gid = (b - 4096) * 256 + threadIdx.x;   // n*256 + k, n<768
        int n = gid >> 8, k = gid & 255;
        float s = (n < DD) ? QSCALE : 1.0f;
        WtQ[(size_t)n * 256 + k] = (u16)f2bf(Wqkv[(size_t)k * D3 + n] * s);
        if (k == 0) biasq[n] = bqkv[n] * s;
    } else if (b < 5120) {               // Wo transpose+bf16
        int gid = (b - 4864) * 256 + threadIdx.x;   // n*256 + k, n<256
        int n = gid >> 8, k = gid & 255;
        WtO[(size_t)n * 256 + k] = (u16)f2bf(Wo[(size_t)k * DD + n]);
        if (k == 0) biaso[n] = bo[n];
    } else {                             // degree histogram
        int e = (b - 5120) * 256 + threadIdx.x;
        atomicAdd(&deg[dst[e]], 1);
    }
}

// ---------------- MFMA GEMM1: qkv = hid @ WtQ^T + bias; -> qb bf16 / kb8 fp8 / h8 fp8 + gb bf16 ----
__global__ __launch_bounds__(256) void mfma_gemm1_kernel(
        const u16* __restrict__ Ab, const u16* __restrict__ Bt,
        const float* __restrict__ bias,
        u16* __restrict__ qb, u8* __restrict__ kb8,
        u8* __restrict__ h8, u16* __restrict__ gb) {
    __shared__ u16 As[128 * 40];
    __shared__ u16 Bs[128 * 40];
    const int tid = threadIdx.x;
    const int m0 = blockIdx.y * 128;
    const int n0 = blockIdx.x * 128;
    const int wave = tid >> 6, lane = tid & 63;
    const int wr = wave >> 1, wc = wave & 1;
    const int lm = lane & 15, quad = lane >> 4;

    f32x4 acc[4][4] = {};
    const int r0 = tid >> 2;
    const int c8 = (tid & 3) * 8;

    for (int k0 = 0; k0 < 256; k0 += 32) {
        #pragma unroll
        for (int s = 0; s < 2; ++s) {
            int r = r0 + s * 64;
            *(uint4*)&As[r * 40 + c8] = *(const uint4*)(Ab + (size_t)(m0 + r) * 256 + k0 + c8);
            *(uint4*)&Bs[r * 40 + c8] = *(const uint4*)(Bt + (size_t)(n0 + r) * 256 + k0 + c8);
        }
        __syncthreads();
        bf16x8 af[4], bfv[4];
        #pragma unroll
        for (int mi = 0; mi < 4; ++mi)
            af[mi] = *(const bf16x8*)&As[(wr * 64 + mi * 16 + lm) * 40 + quad * 8];
        #pragma unroll
        for (int ni = 0; ni < 4; ++ni)
            bfv[ni] = *(const bf16x8*)&Bs[(wc * 64 + ni * 16 + lm) * 40 + quad * 8];
        #pragma unroll
        for (int mi = 0; mi < 4; ++mi)
            #pragma unroll
            for (int ni = 0; ni < 4; ++ni)
                acc[mi][ni] = __builtin_amdgcn_mfma_f32_16x16x32_bf16(
                    af[mi], bfv[ni], acc[mi][ni], 0, 0, 0);
        __syncthreads();
    }

    const int type = n0 >> 8;        // 0=q 1=k 2=v
    const int cb = n0 & 255;
    #pragma unroll
    for (int mi = 0; mi < 4; ++mi) {
        #pragma unroll
        for (int j = 0; j < 4; ++j) {
            int m = m0 + wr * 64 + mi * 16 + quad * 4 + j;
            #pragma unroll
            for (int ni = 0; ni < 4; ++ni) {
                int nl = wc * 64 + ni * 16 + lm;
                float val = acc[mi][ni][j] + bias[n0 + nl];
                size_t off = (size_t)m * 256 + cb + nl;
                if (type == 0) qb[off] = (u16)f2bf(val);
                else if (type == 1) kb8[off] = f2fp8(val);
                else {
                    float hx = val * EXPN1;
                    h8[off] = f2fp8(hx);
                    gb[off] = (u16)f2bf(hx);
                }
            }
        }
    }
}

// ---------------- scan (single block, 1024 threads, 16 nodes each) ----------------
__global__ __launch_bounds__(1024) void scan_kernel(const int* __restrict__ deg,
                                                    int* __restrict__ offs,
                                                    int* __restrict__ cursor, int n) {
    __shared__ int part[1024];
    int t = threadIdx.x;
    int base = t * 16;
    int local[16];
    int s = 0;
    #pragma unroll
    for (int i = 0; i < 16; ++i) { local[i] = s; s += deg[base + i]; }
    part[t] = s;
    __syncthreads();
    for (int d = 1; d < 1024; d <<= 1) {
        int add = (t >= d) ? part[t - d] : 0;
        __syncthreads();
        part[t] += add;
        __syncthreads();
    }
    int excl = part[t] - s;
    #pragma unroll
    for (int i = 0; i < 16; ++i) {
        offs[base + i] = excl + local[i];
        cursor[base + i] = excl + local[i];
    }
    if (t == 1023) offs[n] = excl + s;
}

__global__ void scatter_kernel(const int* __restrict__ src, const int* __restrict__ dst,
                               int* __restrict__ cursor, int* __restrict__ srcs) {
    int e = blockIdx.x * 256 + threadIdx.x;
    int pos = atomicAdd(&cursor[dst[e]], 1);
    srcs[pos] = src[e];
}

// ---------------- fused edge scores + segment softmax: one wave per node ----------------
// lane = (edge_in_chunk<<3) | head. Writes normalized-numerator exp to attn, 1/den to inv.
__global__ __launch_bounds__(256) void edge_softmax_kernel(
        const unsigned* __restrict__ qb, const u8* __restrict__ kb8,
        const int* __restrict__ offs, const int* __restrict__ srcs,
        const float* __restrict__ amask, float* __restrict__ attn,
        float* __restrict__ inv) {
    const int wave = threadIdx.x >> 6, lane = threadIdx.x & 63;
    const int node = blockIdx.x * 4 + wave;
    const int h = lane & 7;
    const int eo = lane >> 3;           // 0..7: edge offset within chunk
    const int beg = offs[node], end = offs[node + 1];
    // preload q row (head h) of this node: 32 bf16 = 16 dwords
    const uint4* qp = (const uint4*)(qb + (size_t)node * 128 + h * 16);
    uint4 q0 = qp[0], q1 = qp[1], q2 = qp[2], q3 = qp[3];
    unsigned qq[16] = {q0.x, q0.y, q0.z, q0.w, q1.x, q1.y, q1.z, q1.w,
                       q2.x, q2.y, q2.z, q2.w, q3.x, q3.y, q3.z, q3.w};
    const bool dvalid = amask[node] >= 0.0f;

    // phase 1: raw scores -> attn, running per-lane max
    float m = -1e30f;
    for (int i0 = beg; i0 < end; i0 += 8) {
        int i = i0 + eo;
        if (i < end) {
            int s = srcs[i];
            const uint4* kp = (const uint4*)(kb8 + (size_t)s * 256 + h * 32);
            uint4 k0 = kp[0], k1 = kp[1];
            unsigned kk[8] = {k0.x, k0.y, k0.z, k0.w, k1.x, k1.y, k1.z, k1.w};
            float acc = 0.0f;
            #pragma unroll
            for (int t = 0; t < 8; ++t) {
                f32x2 a = __builtin_amdgcn_cvt_pk_f32_fp8(kk[t], false);
                f32x2 b = __builtin_amdgcn_cvt_pk_f32_fp8(kk[t], true);
                acc += a.x * bf_lo(qq[2 * t]) + a.y * bf_hi(qq[2 * t]);
                acc += b.x * bf_lo(qq[2 * t + 1]) + b.y * bf_hi(qq[2 * t + 1]);
            }
            bool valid = dvalid && (amask[s] >= 0.0f);
            float score = valid ? acc : -10000.0f;
            attn[(size_t)i * 8 + h] = score;
            m = fmaxf(m, score);
        }
    }
    // per-head max across the 8 lanes sharing h
    m = fmaxf(m, __shfl_xor(m, 8));
    m = fmaxf(m, __shfl_xor(m, 16));
    m = fmaxf(m, __shfl_xor(m, 32));

    // phase 2: exp + sum (attn is L1-hot)
    float den = 0.0f;
    for (int i0 = beg; i0 < end; i0 += 8) {
        int i = i0 + eo;
        if (i < end) {
            float es = __expf(attn[(size_t)i * 8 + h] - m);
            attn[(size_t)i * 8 + h] = es;
            den += es;
        }
    }
    den += __shfl_xor(den, 8);
    den += __shfl_xor(den, 16);
    den += __shfl_xor(den, 32);
    if (lane < 8) inv[node * 8 + h] = (end > beg) ? 1.0f / den : 0.0f;
}

// ---------------- diffusion: one wave/node, 4 ch/thread, fp8 h gathers, bf16 gather RMW ----
__global__ void diffuse_kernel(const int* __restrict__ offs, const int* __restrict__ srcs,
                               const float* __restrict__ attn, const float* __restrict__ inv,
                               const unsigned* __restrict__ hcur, unsigned* __restrict__ hnext,
                               uint2* __restrict__ gb, float fact) {
    int gid = blockIdx.x * 256 + threadIdx.x;
    int node = gid >> 6;
    int j2 = gid & 63;          // channels 4*j2 .. 4*j2+3
    int h = j2 >> 3;
    int beg = offs[node], end = offs[node + 1];
    float a0 = 0.0f, a1 = 0.0f, a2 = 0.0f, a3 = 0.0f;
    int i = beg;
    for (; i + 8 <= end; i += 8) {
        int sarr[8]; float aarr[8]; unsigned hv[8];
        #pragma unroll
        for (int t = 0; t < 8; ++t) {
            sarr[t] = srcs[i + t];
            aarr[t] = attn[(size_t)(i + t) * 8 + h];
        }
        #pragma unroll
        for (int t = 0; t < 8; ++t) hv[t] = hcur[(size_t)sarr[t] * 64 + j2];
        #pragma unroll
        for (int t = 0; t < 8; ++t) {
            float a = aarr[t];
            f32x2 lo = __builtin_amdgcn_cvt_pk_f32_fp8(hv[t], false);
            f32x2 hi = __builtin_amdgcn_cvt_pk_f32_fp8(hv[t], true);
            a0 += a * lo.x; a1 += a * lo.y;
            a2 += a * hi.x; a3 += a * hi.y;
        }
    }
    if (i < end) {
        int cnt = end - i;
        int sarr[8]; float aarr[8]; unsigned hv[8];
        #pragma unroll
        for (int t = 0; t < 8; ++t) if (t < cnt) {
            sarr[t] = srcs[i + t];
            aarr[t] = attn[(size_t)(i + t) * 8 + h];
        }
        #pragma unroll
        for (int t = 0; t < 8; ++t) if (t < cnt) hv[t] = hcur[(size_t)sarr[t] * 64 + j2];
        #pragma unroll
        for (int t = 0; t < 8; ++t) if (t < cnt) {
            float a = aarr[t];
            f32x2 lo = __builtin_amdgcn_cvt_pk_f32_fp8(hv[t], false);
            f32x2 hi = __builtin_amdgcn_cvt_pk_f32_fp8(hv[t], true);
            a0 += a * lo.x; a1 += a * lo.y;
            a2 += a * hi.x; a3 += a * hi.y;
        }
    }
    float iv = inv[node * 8 + h];
    a0 *= iv; a1 *= iv; a2 *= iv; a3 *= iv;
    if (hnext) {
        int pk = __builtin_amdgcn_cvt_pk_fp8_f32(a0, a1, 0, false);
        pk = __builtin_amdgcn_cvt_pk_fp8_f32(a2, a3, pk, true);
        hnext[(size_t)node * 64 + j2] = (unsigned)pk;
    }
    uint2* gp = gb + (size_t)node * 64 + j2;
    uint2 g = *gp;
    float g0 = bf_lo(g.x) + fact * a0;
    float g1 = bf_hi(g.x) + fact * a1;
    float g2 = bf_lo(g.y) + fact * a2;
    float g3 = bf_hi(g.y) + fact * a3;
    *gp = make_uint2(pack2bf(g0, g1), pack2bf(g2, g3));
}

// ---------------- GEMM2 (64x256 tile) + residual + fused LayerNorm ----------------
__global__ __launch_bounds__(256) void gemm2_ln_kernel(
        const u16* __restrict__ Ab, const u16* __restrict__ Bt,
        const float* __restrict__ bias, const float* __restrict__ resid,
        const float* __restrict__ gamma, const float* __restrict__ beta,
        float* __restrict__ out) {
    __shared__ u16 As[64 * 40];
    __shared__ u16 Bs[256 * 40];
    const int tid = threadIdx.x;
    const int m0 = blockIdx.x * 64;
    const int wave = tid >> 6, lane = tid & 63;
    const int lm = lane & 15, quad = lane >> 4;

    f32x4 acc[16] = {};
    for (int k0 = 0; k0 < 256; k0 += 32) {
        *(uint4*)&As[(tid >> 2) * 40 + (tid & 3) * 8] =
            *(const uint4*)(Ab + (size_t)(m0 + (tid >> 2)) * 256 + k0 + (tid & 3) * 8);
        {
            const uint4* srcp = (const uint4*)(Bt + (size_t)tid * 256 + k0);
            uint4* dstp = (uint4*)&Bs[tid * 40];
            dstp[0] = srcp[0]; dstp[1] = srcp[1]; dstp[2] = srcp[2]; dstp[3] = srcp[3];
        }
        __syncthreads();
        bf16x8 af = *(const bf16x8*)&As[(wave * 16 + lm) * 40 + quad * 8];
        #pragma unroll
        for (int ni = 0; ni < 16; ++ni) {
            bf16x8 bfv = *(const bf16x8*)&Bs[(ni * 16 + lm) * 40 + quad * 8];
            acc[ni] = __builtin_amdgcn_mfma_f32_16x16x32_bf16(af, bfv, acc[ni], 0, 0, 0);
        }
        __syncthreads();
    }

    const int mrow = m0 + wave * 16 + quad * 4;
    float ga[16], be[16];
    float rowsum[4] = {}, rowsq[4] = {};
    #pragma unroll
    for (int ni = 0; ni < 16; ++ni) {
        int col = ni * 16 + lm;
        float bia = bias[col];
        ga[ni] = gamma[col]; be[ni] = beta[col];
        #pragma unroll
        for (int j = 0; j < 4; ++j) {
            float val = acc[ni][j] + bia + resid[(size_t)(mrow + j) * 256 + col];
            acc[ni][j] = val;
            rowsum[j] += val;
            rowsq[j] += val * val;
        }
    }
    #pragma unroll
    for (int j = 0; j < 4; ++j) {
        #pragma unroll
        for (int msk = 1; msk <= 8; msk <<= 1) {
            rowsum[j] += __shfl_xor(rowsum[j], msk);
            rowsq[j] += __shfl_xor(rowsq[j], msk);
        }
    }
    float mu[4], rstd[4];
    #pragma unroll
    for (int j = 0; j < 4; ++j) {
        mu[j] = rowsum[j] * (1.0f / 256.0f);
        float var = rowsq[j] * (1.0f / 256.0f) - mu[j] * mu[j];
        rstd[j] = 1.0f / sqrtf(var + LN_EPS);
    }
    #pragma unroll
    for (int ni = 0; ni < 16; ++ni) {
        int col = ni * 16 + lm;
        #pragma unroll
        for (int j = 0; j < 4; ++j)
            out[(size_t)(mrow + j) * 256 + col] = (acc[ni][j] - mu[j]) * rstd[j] * ga[ni] + be[ni];
    }
}

extern "C" void kernel_launch(void* const* d_in, const int* in_sizes, int n_in,
                              void* d_out, int out_size, void* d_ws, size_t ws_size,
                              hipStream_t stream) {
    const float* hidden = (const float*)d_in[0];
    const float* amask  = (const float*)d_in[1];
    const int*   src    = (const int*)d_in[2];
    const int*   dst    = (const int*)d_in[3];
    const float* Wqkv   = (const float*)d_in[4];
    const float* bqkv   = (const float*)d_in[5];
    const float* Wo     = (const float*)d_in[6];
    const float* bo     = (const float*)d_in[7];
    const float* gamma  = (const float*)d_in[8];
    const float* beta   = (const float*)d_in[9];
    float* out = (float*)d_out;

    char* p = (char*)d_ws;
    u16*      hidb   = (u16*)p;      p += (size_t)NN * DD * 2;     // 8 MB
    u16*      WtQ    = (u16*)p;      p += (size_t)D3 * DD * 2;
    u16*      WtO    = (u16*)p;      p += (size_t)DD * DD * 2;
    float*    biasq  = (float*)p;    p += (size_t)D3 * 4;
    float*    biaso  = (float*)p;    p += (size_t)DD * 4;
    u16*      qb     = (u16*)p;      p += (size_t)NN * DD * 2;     // 8 MB bf16
    u8*       kb8    = (u8*)p;       p += (size_t)NN * DD;         // 4 MB fp8
    u8*       h8A    = (u8*)p;       p += (size_t)NN * DD;         // 4 MB fp8
    u8*       h8B    = (u8*)p;       p += (size_t)NN * DD;         // 4 MB fp8
    u16*      gb     = (u16*)p;      p += (size_t)NN * DD * 2;     // 8 MB bf16 gather acc
    float*    attn   = (float*)p;    p += (size_t)EE * HH * 4;     // 8 MB
    float*    inv    = (float*)p;    p += (size_t)NN * HH * 4;     // 0.5 MB
    int*      deg    = (int*)p;      p += (size_t)NN * 4;
    int*      offs   = (int*)p;      p += (size_t)(NN + 1) * 4;
    int*      cursor = (int*)p;      p += (size_t)NN * 4;
    int*      srcs   = (int*)p;      p += (size_t)EE * 4;

    // 1. zero degree histogram, then fused prep (convs + hist)
    hipMemsetAsync(deg, 0, (size_t)NN * 4, stream);
    prep_kernel<<<6144, 256, 0, stream>>>(hidden, (unsigned*)hidb,
                                          Wqkv, bqkv, WtQ, biasq,
                                          Wo, bo, WtO, biaso, dst, deg);

    // 2. CSR: scan + scatter
    scan_kernel<<<1, 1024, 0, stream>>>(deg, offs, cursor, NN);
    scatter_kernel<<<EE / 256, 256, 0, stream>>>(src, dst, cursor, srcs);

    // 3. QKV projection (MFMA), fused epilogue
    mfma_gemm1_kernel<<<dim3(D3 / 128, NN / 128), 256, 0, stream>>>(
        hidb, WtQ, biasq, qb, kb8, h8A, gb);

    // 4. fused edge scores + segment softmax (one wave per node)
    edge_softmax_kernel<<<NN / 4, 256, 0, stream>>>(
        (const unsigned*)qb, kb8, offs, srcs, amask, attn, inv);

    // 5. diffusion: gb = h0 + h1 + h2/2 + h3/6 (bf16 RMW in place)
    diffuse_kernel<<<(NN * 64) / 256, 256, 0, stream>>>(
        offs, srcs, attn, inv, (const unsigned*)h8A, (unsigned*)h8B, (uint2*)gb, 1.0f);
    diffuse_kernel<<<(NN * 64) / 256, 256, 0, stream>>>(
        offs, srcs, attn, inv, (const unsigned*)h8B, (unsigned*)h8A, (uint2*)gb, 0.5f);
    diffuse_kernel<<<(NN * 64) / 256, 256, 0, stream>>>(
        offs, srcs, attn, inv, (const unsigned*)h8A, nullptr, (uint2*)gb, 1.0f / 6.0f);

    // 6. output projection + residual + fused LayerNorm -> out
    gemm2_ln_kernel<<<NN / 64, 256, 0, stream>>>(
        gb, WtO, biaso, hidden, gamma, beta, out);
}